// Round 7
// baseline (5936.320 us; speedup 1.0000x reference)
//
#include <hip/hip_runtime.h>
#include <hip/hip_bf16.h>
#include <cmath>

// Problem constants
#define BATCH 16
#define SEQ 256
#define EMBED 512
#define HIDDEN 1024
#define GATES 4096       // 4*HIDDEN
#define VOCAB 32000
#define MROWS 4096       // BATCH*SEQ
#define LOGITS_SZ 131072000  // 16*256*32000

#define NSLOT 257                    // h-history slots (init + 256 steps)
#define SEQ_SLOTU16 16384            // u16 per slot: 16 batch x 1024
#define SEQ_LOU16 (NSLOT * SEQ_SLOTU16)

typedef unsigned int u32;
typedef unsigned short u16;
typedef unsigned long long u64;
typedef __attribute__((ext_vector_type(8))) short bf16x8;
typedef __attribute__((ext_vector_type(4))) float f32x4;

#define AS1 __attribute__((address_space(1)))
#define AS3 __attribute__((address_space(3)))

// ---------------- helpers ----------------
__device__ __forceinline__ u32 f2bf(float f) {          // RNE fp32->bf16 (bits)
    u32 u = __float_as_uint(f);
    return (u + 0x7fffu + ((u >> 16) & 1u)) >> 16;
}
__device__ __forceinline__ float bf2f(u32 b) { return __uint_as_float(b << 16); }

__device__ __forceinline__ u64 aload(const u64* p) {
    return __hip_atomic_load(p, __ATOMIC_RELAXED, __HIP_MEMORY_SCOPE_AGENT);
}
__device__ __forceinline__ void astore(u64* p, u64 v) {
    __hip_atomic_store(p, v, __ATOMIC_RELAXED, __HIP_MEMORY_SCOPE_AGENT);
}

// ---------------- embedding gather ----------------
__global__ void embed_kernel(const int* __restrict__ x, const float* __restrict__ emb,
                             float* __restrict__ X0) {
    int r = blockIdx.x;            // r = s*16 + b
    int s = r >> 4, b = r & 15;
    int tok = x[b * SEQ + s];
    const float4* src = (const float4*)(emb + (size_t)tok * EMBED);
    float4* dst = (float4*)(X0 + (size_t)r * EMBED);
    for (int i = threadIdx.x; i < EMBED / 4; i += blockDim.x) dst[i] = src[i];
}

// ---------------- fp32 GEMM: C[M,N] = A[M,K] @ B[N,K]^T + b1 + b2 ----------------
__global__ __launch_bounds__(256) void gemm_bt(
    const float* __restrict__ A, const float* __restrict__ B,
    const float* __restrict__ b1, const float* __restrict__ b2,
    float* __restrict__ C, int M, int N, int K, int perm) {
    __shared__ float As[8][128];
    __shared__ float Bs[8][128];
    int tid = threadIdx.x;
    int bm = blockIdx.y, bn = blockIdx.x;
    int arow = tid >> 1;
    int ak4 = (tid & 1) * 4;
    const float* Ag = A + (size_t)(bm * 128 + arow) * K + ak4;
    const float* Bg = B + (size_t)(bn * 128 + arow) * K + ak4;
    int tx = tid & 15, ty = tid >> 4;

    float acc[8][8];
#pragma unroll
    for (int i = 0; i < 8; i++)
#pragma unroll
        for (int j = 0; j < 8; j++) acc[i][j] = 0.f;

    for (int k0 = 0; k0 < K; k0 += 8) {
        float4 a4 = *(const float4*)(Ag + k0);
        float4 b4 = *(const float4*)(Bg + k0);
        __syncthreads();
        As[ak4 + 0][arow] = a4.x; As[ak4 + 1][arow] = a4.y;
        As[ak4 + 2][arow] = a4.z; As[ak4 + 3][arow] = a4.w;
        Bs[ak4 + 0][arow] = b4.x; Bs[ak4 + 1][arow] = b4.y;
        Bs[ak4 + 2][arow] = b4.z; Bs[ak4 + 3][arow] = b4.w;
        __syncthreads();
#pragma unroll
        for (int k = 0; k < 8; k++) {
            float av[8], bv[8];
            *(float4*)(av + 0) = *(const float4*)&As[k][ty * 8 + 0];
            *(float4*)(av + 4) = *(const float4*)&As[k][ty * 8 + 4];
            *(float4*)(bv + 0) = *(const float4*)&Bs[k][tx * 8 + 0];
            *(float4*)(bv + 4) = *(const float4*)&Bs[k][tx * 8 + 4];
#pragma unroll
            for (int i = 0; i < 8; i++)
#pragma unroll
                for (int j = 0; j < 8; j++) acc[i][j] += av[i] * bv[j];
        }
    }

#pragma unroll
    for (int i = 0; i < 8; i++) {
        int r = bm * 128 + ty * 8 + i;
        int orow = perm ? ((r & 15) * SEQ + (r >> 4)) : r;
#pragma unroll
        for (int j = 0; j < 8; j += 4) {
            int c = bn * 128 + tx * 8 + j;
            float4 v;
            float bb0 = (b1 ? b1[c + 0] : 0.f) + (b2 ? b2[c + 0] : 0.f);
            float bb1 = (b1 ? b1[c + 1] : 0.f) + (b2 ? b2[c + 1] : 0.f);
            float bb2 = (b1 ? b1[c + 2] : 0.f) + (b2 ? b2[c + 2] : 0.f);
            float bb3 = (b1 ? b1[c + 3] : 0.f) + (b2 ? b2[c + 3] : 0.f);
            v.x = acc[i][j + 0] + bb0;
            v.y = acc[i][j + 1] + bb1;
            v.z = acc[i][j + 2] + bb2;
            v.w = acc[i][j + 3] + bb3;
            *(float4*)&C[(size_t)orow * N + c] = v;
        }
    }
}

// ---------------- fp32 -> bf16 conversion (hi only, for fc_W) ----------------
__global__ __launch_bounds__(256) void f32_to_bf16_kernel(
    const float* __restrict__ in, u16* __restrict__ out, int n8) {
    for (int i = blockIdx.x * 256 + threadIdx.x; i < n8; i += gridDim.x * 256) {
        float4 a = ((const float4*)in)[2 * (size_t)i + 0];
        float4 b = ((const float4*)in)[2 * (size_t)i + 1];
        uint4 o;
        o.x = f2bf(a.x) | (f2bf(a.y) << 16);
        o.y = f2bf(a.z) | (f2bf(a.w) << 16);
        o.z = f2bf(b.x) | (f2bf(b.y) << 16);
        o.w = f2bf(b.z) | (f2bf(b.w) << 16);
        ((uint4*)out)[i] = o;
    }
}

// ---------------- fp32 -> bf16 hi+lo split (for W_ih1) ----------------
__global__ __launch_bounds__(256) void f32_to_bf16hl_kernel(
    const float* __restrict__ in, u16* __restrict__ hi, u16* __restrict__ lo, int n4) {
    for (int i = blockIdx.x * 256 + threadIdx.x; i < n4; i += gridDim.x * 256) {
        float4 a = ((const float4*)in)[i];
        u32 h0 = f2bf(a.x), h1 = f2bf(a.y), h2 = f2bf(a.z), h3 = f2bf(a.w);
        u64 hq = (u64)(h0 | (h1 << 16)) | ((u64)(h2 | (h3 << 16)) << 32);
        u32 l0 = f2bf(a.x - bf2f(h0)), l1 = f2bf(a.y - bf2f(h1));
        u32 l2 = f2bf(a.z - bf2f(h2)), l3 = f2bf(a.w - bf2f(h3));
        u64 lq = (u64)(l0 | (l1 << 16)) | ((u64)(l2 | (l3 << 16)) << 32);
        ((u64*)hi)[i] = hq;
        ((u64*)lo)[i] = lq;
    }
}

// ---------------- bf16 MFMA FC GEMM ----------------
__global__ __launch_bounds__(256) void fc_mfma(
    const u16* __restrict__ Abf,   // [MROWS][1024] bf16
    const u16* __restrict__ Bbf,   // [VOCAB][1024] bf16
    const float* __restrict__ bias,
    float* __restrict__ C) {
    const int K = HIDDEN;
    const int N = VOCAB;
    __shared__ char smem[16384];
    char* As = smem;
    char* Bs = smem + 8192;

    int tid = threadIdx.x;
    int w = tid >> 6, l = tid & 63;
    int bn = blockIdx.x, bm = blockIdx.y;
    int wr = w >> 1, wc = w & 1;
    int lr = l & 15, lk = l >> 4;

    f32x4 acc[4][4];
#pragma unroll
    for (int m = 0; m < 4; m++)
#pragma unroll
        for (int n = 0; n < 4; n++) acc[m][n] = {0.f, 0.f, 0.f, 0.f};

    int srow = tid >> 2, skc = (tid & 3) * 8;
    const u16* ga0 = Abf + (size_t)(bm * 128 + srow) * K + skc;
    const u16* ga1 = Abf + (size_t)(bm * 128 + 64 + srow) * K + skc;
    const u16* gb0 = Bbf + (size_t)(bn * 128 + srow) * K + skc;
    const u16* gb1 = Bbf + (size_t)(bn * 128 + 64 + srow) * K + skc;
    char* la0 = As + w * 1024;
    char* la1 = As + 4096 + w * 1024;
    char* lb0 = Bs + w * 1024;
    char* lb1 = Bs + 4096 + w * 1024;

    int afo[4], bfo[4];
#pragma unroll
    for (int m = 0; m < 4; m++) afo[m] = (wr * 64 + m * 16 + lr) * 64 + lk * 16;
#pragma unroll
    for (int n = 0; n < 4; n++) bfo[n] = (wc * 64 + n * 16 + lr) * 64 + lk * 16;

    for (int k0 = 0; k0 < K; k0 += 32) {
        __syncthreads();
        __builtin_amdgcn_global_load_lds((const AS1 u32*)(const void*)(ga0 + k0),
                                         (AS3 u32*)(void*)la0, 16, 0, 0);
        __builtin_amdgcn_global_load_lds((const AS1 u32*)(const void*)(ga1 + k0),
                                         (AS3 u32*)(void*)la1, 16, 0, 0);
        __builtin_amdgcn_global_load_lds((const AS1 u32*)(const void*)(gb0 + k0),
                                         (AS3 u32*)(void*)lb0, 16, 0, 0);
        __builtin_amdgcn_global_load_lds((const AS1 u32*)(const void*)(gb1 + k0),
                                         (AS3 u32*)(void*)lb1, 16, 0, 0);
        __syncthreads();

        bf16x8 af[4], bfr[4];
#pragma unroll
        for (int m = 0; m < 4; m++) af[m] = *(const bf16x8*)(As + afo[m]);
#pragma unroll
        for (int n = 0; n < 4; n++) bfr[n] = *(const bf16x8*)(Bs + bfo[n]);
#pragma unroll
        for (int m = 0; m < 4; m++)
#pragma unroll
            for (int n = 0; n < 4; n++)
                acc[m][n] = __builtin_amdgcn_mfma_f32_16x16x32_bf16(
                    af[m], bfr[n], acc[m][n], 0, 0, 0);
    }

    int rbase = bm * 128 + wr * 64 + lk * 4;
    int cbase = bn * 128 + wc * 64 + lr;
#pragma unroll
    for (int m = 0; m < 4; m++) {
#pragma unroll
        for (int n = 0; n < 4; n++) {
            int c = cbase + n * 16;
            float bb = bias[c];
#pragma unroll
            for (int j = 0; j < 4; j++) {
                int r = rbase + m * 16 + j;
                int orow = (r & 15) * SEQ + (r >> 4);   // [B,S,V] layout
                C[(size_t)orow * N + c] = acc[m][n][j] + bb;
            }
        }
    }
}

// ---------------- fused 2-layer persistent LSTM (pipelined) -------------------
// 256 blocks x 256 threads. Blocks 0..127: layer 0 (8 units each); 128..255:
// layer 1. Global step s: L0 does t=s, L1 does t=s-1 (pipeline). h histories in
// per-slot seq buffers (hi/lo bf16, agent atomics). L1's input projection is
// folded in as streamed-Wih hi/lo MFMA. One arrive/poll barrier per step: 256
// barriers total (vs 512 for split layers).
__global__ __launch_bounds__(256) void lstm_fused(
    const float* __restrict__ Whh0, const float* __restrict__ Whh1,
    const float* __restrict__ G0,        // [4096][4096] rows t*16+b (L0 x-proj + biases)
    const u16* __restrict__ wih_hi,      // [4096][1024] bf16 hi of W_ih1
    const u16* __restrict__ wih_lo,
    const float* __restrict__ bi1, const float* __restrict__ bh1,
    const float* __restrict__ c0in,      // [2][16][1024]
    float* __restrict__ c_tail, float* __restrict__ h_tail,  // [2][16][1024]
    u16* __restrict__ seq0, u16* __restrict__ seq1,          // [NSLOT hi | NSLOT lo]
    u32* __restrict__ arrive) {
    __shared__ __align__(16) char lds[139264];
    char* Whi = lds;                   // [32 rows][2048B] swizzled Whh hi
    char* Wlo = lds + 65536;           // lo
    float* Pw = (float*)(lds + 131072);  // [4 wave][2 ct][64 lane][4] partials

    const int tid = threadIdx.x;
    const int bid = blockIdx.x;
    const int role = bid >> 7;         // 0 = layer0, 1 = layer1
    const int rb = bid & 127;
    const int j0 = rb * 8;             // 8 hidden units per block
    const int w = tid >> 6, l = tid & 63;
    const int lb = l & 15, hi4 = l >> 4, xr = l & 7;

    // ---- one-time: stage Whh slice (32 gate-cols x 1024) as hi/lo, swizzled ----
    const float* Whh = role ? Whh1 : Whh0;
#pragma unroll
    for (int i = 0; i < 16; i++) {
        int q = i * 256 + tid;            // 16B chunk id 0..4095
        int row = q >> 7, cin = q & 127;  // row = gate-col-in-block (0..31)
        int nrow = (row >> 3) * HIDDEN + j0 + (row & 7);
        const float* src = Whh + (size_t)nrow * HIDDEN + cin * 8;
        int dst = row * 2048 + ((cin ^ (row & 7)) << 4);
        u32 hw[4], lw[4];
#pragma unroll
        for (int e = 0; e < 4; e++) {
            float x0 = src[2 * e], x1 = src[2 * e + 1];
            u32 hb0 = f2bf(x0), hb1 = f2bf(x1);
            hw[e] = hb0 | (hb1 << 16);
            lw[e] = f2bf(x0 - bf2f(hb0)) | (f2bf(x1 - bf2f(hb1)) << 16);
        }
        *(uint4*)(Whi + dst) = make_uint4(hw[0], hw[1], hw[2], hw[3]);
        *(uint4*)(Wlo + dst) = make_uint4(lw[0], lw[1], lw[2], lw[3]);
    }

    // pointwise state (wave 0): lane l -> batch lb, units (hi4) and (4+hi4)
    float cA = 0.f, cB = 0.f;
    float gA0 = 0, gA1 = 0, gA2 = 0, gA3 = 0, gB0 = 0, gB1 = 0, gB2 = 0, gB3 = 0;
    if (tid < 64) {
        cA = c0in[role * 16384 + lb * HIDDEN + j0 + hi4];
        cB = c0in[role * 16384 + lb * HIDDEN + j0 + 4 + hi4];
        if (role == 0) {
            const float* gp = G0 + (size_t)lb * GATES + j0;   // t = 0
            gA0 = gp[hi4];              gB0 = gp[4 + hi4];
            gA1 = gp[HIDDEN + hi4];     gB1 = gp[HIDDEN + 4 + hi4];
            gA2 = gp[2 * HIDDEN + hi4]; gB2 = gp[2 * HIDDEN + 4 + hi4];
            gA3 = gp[3 * HIDDEN + hi4]; gB3 = gp[3 * HIDDEN + 4 + hi4];
        } else {                        // constant bias sum for layer 1
            gA0 = bi1[j0 + hi4] + bh1[j0 + hi4];
            gB0 = bi1[j0 + 4 + hi4] + bh1[j0 + 4 + hi4];
            gA1 = bi1[HIDDEN + j0 + hi4] + bh1[HIDDEN + j0 + hi4];
            gB1 = bi1[HIDDEN + j0 + 4 + hi4] + bh1[HIDDEN + j0 + 4 + hi4];
            gA2 = bi1[2 * HIDDEN + j0 + hi4] + bh1[2 * HIDDEN + j0 + hi4];
            gB2 = bi1[2 * HIDDEN + j0 + 4 + hi4] + bh1[2 * HIDDEN + j0 + 4 + hi4];
            gA3 = bi1[3 * HIDDEN + j0 + hi4] + bh1[3 * HIDDEN + j0 + hi4];
            gB3 = bi1[3 * HIDDEN + j0 + 4 + hi4] + bh1[3 * HIDDEN + j0 + 4 + hi4];
        }
    }
    __syncthreads();

    const u64* s0h = (const u64*)seq0;
    const u64* s0l = (const u64*)(seq0 + SEQ_LOU16);
    const u64* s1h = (const u64*)seq1;
    const u64* s1l = (const u64*)(seq1 + SEQ_LOU16);
    const int fb = lb * 256 + w * 64 + hi4 * 2;   // u64 base within a slot

    for (int s = 0; s <= SEQ; s++) {
        const bool act = role ? (s >= 1) : (s < SEQ);
        if (act) {
            f32x4 a0[2], a1[2], a2[2];
#pragma unroll
            for (int ct = 0; ct < 2; ct++) {
                a0[ct] = {0.f, 0.f, 0.f, 0.f};
                a1[ct] = {0.f, 0.f, 0.f, 0.f};
                a2[ct] = {0.f, 0.f, 0.f, 0.f};
            }

            // B-frags from seq0 slot s (L0 state / L1 input o0[t1])
            u64 xh[16], xl[16];
            {
                const int base = s * 4096 + fb;
#pragma unroll
                for (int ss = 0; ss < 8; ss++) {
                    xh[2 * ss + 0] = aload(s0h + base + ss * 8 + 0);
                    xh[2 * ss + 1] = aload(s0h + base + ss * 8 + 1);
                    xl[2 * ss + 0] = aload(s0l + base + ss * 8 + 0);
                    xl[2 * ss + 1] = aload(s0l + base + ss * 8 + 1);
                }
            }
            if (role == 0) {
                // recurrent: A = LDS Whh0, B = x
#pragma unroll
                for (int ss = 0; ss < 8; ss++) {
                    const int s32 = w * 8 + ss;
                    union { u64 q[2]; bf16x8 v; } bh_, bl_;
                    bh_.q[0] = xh[2 * ss]; bh_.q[1] = xh[2 * ss + 1];
                    bl_.q[0] = xl[2 * ss]; bl_.q[1] = xl[2 * ss + 1];
#pragma unroll
                    for (int ct = 0; ct < 2; ct++) {
                        const int off = (ct * 16 + lb) * 2048 + (((s32 * 4 + hi4) ^ xr) << 4);
                        bf16x8 ah = *(const bf16x8*)(Whi + off);
                        bf16x8 al = *(const bf16x8*)(Wlo + off);
                        a0[ct] = __builtin_amdgcn_mfma_f32_16x16x32_bf16(ah, bh_.v, a0[ct], 0, 0, 0);
                        a1[ct] = __builtin_amdgcn_mfma_f32_16x16x32_bf16(al, bh_.v, a1[ct], 0, 0, 0);
                        a2[ct] = __builtin_amdgcn_mfma_f32_16x16x32_bf16(ah, bl_.v, a2[ct], 0, 0, 0);
                    }
                }
            } else {
                // h1 state frags from seq1 slot s-1
                u64 yh[16], yl[16];
                {
                    const int base = (s - 1) * 4096 + fb;
#pragma unroll
                    for (int ss = 0; ss < 8; ss++) {
                        yh[2 * ss + 0] = aload(s1h + base + ss * 8 + 0);
                        yh[2 * ss + 1] = aload(s1h + base + ss * 8 + 1);
                        yl[2 * ss + 0] = aload(s1l + base + ss * 8 + 0);
                        yl[2 * ss + 1] = aload(s1l + base + ss * 8 + 1);
                    }
                }
                // input projection: A = streamed wih frags, B = x (o0[t1])
#pragma unroll
                for (int ss = 0; ss < 8; ss++) {
                    const int k = w * 256 + ss * 32 + hi4 * 8;
                    union { u64 q[2]; bf16x8 v; } bh_, bl_;
                    bh_.q[0] = xh[2 * ss]; bh_.q[1] = xh[2 * ss + 1];
                    bl_.q[0] = xl[2 * ss]; bl_.q[1] = xl[2 * ss + 1];
#pragma unroll
                    for (int ct = 0; ct < 2; ct++) {
                        const int c = ct * 16 + lb;
                        const size_t ge = (size_t)((c >> 3) * HIDDEN + j0 + (c & 7)) * HIDDEN + k;
                        bf16x8 ah = *(const bf16x8*)(wih_hi + ge);
                        bf16x8 al = *(const bf16x8*)(wih_lo + ge);
                        a0[ct] = __builtin_amdgcn_mfma_f32_16x16x32_bf16(ah, bh_.v, a0[ct], 0, 0, 0);
                        a1[ct] = __builtin_amdgcn_mfma_f32_16x16x32_bf16(al, bh_.v, a1[ct], 0, 0, 0);
                        a2[ct] = __builtin_amdgcn_mfma_f32_16x16x32_bf16(ah, bl_.v, a2[ct], 0, 0, 0);
                    }
                }
                // recurrent: A = LDS Whh1, B = y
#pragma unroll
                for (int ss = 0; ss < 8; ss++) {
                    const int s32 = w * 8 + ss;
                    union { u64 q[2]; bf16x8 v; } bh_, bl_;
                    bh_.q[0] = yh[2 * ss]; bh_.q[1] = yh[2 * ss + 1];
                    bl_.q[0] = yl[2 * ss]; bl_.q[1] = yl[2 * ss + 1];
#pragma unroll
                    for (int ct = 0; ct < 2; ct++) {
                        const int off = (ct * 16 + lb) * 2048 + (((s32 * 4 + hi4) ^ xr) << 4);
                        bf16x8 ah = *(const bf16x8*)(Whi + off);
                        bf16x8 al = *(const bf16x8*)(Wlo + off);
                        a0[ct] = __builtin_amdgcn_mfma_f32_16x16x32_bf16(ah, bh_.v, a0[ct], 0, 0, 0);
                        a1[ct] = __builtin_amdgcn_mfma_f32_16x16x32_bf16(al, bh_.v, a1[ct], 0, 0, 0);
                        a2[ct] = __builtin_amdgcn_mfma_f32_16x16x32_bf16(ah, bl_.v, a2[ct], 0, 0, 0);
                    }
                }
            }
            f32x4 v0 = a0[0] + a1[0] + a2[0];
            f32x4 v1 = a0[1] + a1[1] + a2[1];
            *(f32x4*)&Pw[((w * 2 + 0) * 64 + l) * 4] = v0;
            *(f32x4*)&Pw[((w * 2 + 1) * 64 + l) * 4] = v1;
            __syncthreads();

            if (tid < 64) {
                float hvA, hvB;
                {   // unit A = hi4
                    float pre[4];
#pragma unroll
                    for (int g = 0; g < 4; g++) {
                        const int ct = g >> 1;
                        const int r = (g & 1) * 8 + hi4;
                        const int ll = ((r >> 2) << 4) | lb;
                        const int jw = r & 3;
                        pre[g] = Pw[((0 * 2 + ct) * 64 + ll) * 4 + jw]
                               + Pw[((1 * 2 + ct) * 64 + ll) * 4 + jw]
                               + Pw[((2 * 2 + ct) * 64 + ll) * 4 + jw]
                               + Pw[((3 * 2 + ct) * 64 + ll) * 4 + jw];
                    }
                    const float ig = 1.f / (1.f + __expf(-(pre[0] + gA0)));
                    const float fg = 1.f / (1.f + __expf(-(pre[1] + gA1)));
                    const float gt = tanhf(pre[2] + gA2);
                    const float og = 1.f / (1.f + __expf(-(pre[3] + gA3)));
                    cA = fg * cA + ig * gt;
                    hvA = og * tanhf(cA);
                }
                {   // unit B = 4 + hi4
                    float pre[4];
#pragma unroll
                    for (int g = 0; g < 4; g++) {
                        const int ct = g >> 1;
                        const int r = (g & 1) * 8 + 4 + hi4;
                        const int ll = ((r >> 2) << 4) | lb;
                        const int jw = r & 3;
                        pre[g] = Pw[((0 * 2 + ct) * 64 + ll) * 4 + jw]
                               + Pw[((1 * 2 + ct) * 64 + ll) * 4 + jw]
                               + Pw[((2 * 2 + ct) * 64 + ll) * 4 + jw]
                               + Pw[((3 * 2 + ct) * 64 + ll) * 4 + jw];
                    }
                    const float ig = 1.f / (1.f + __expf(-(pre[0] + gB0)));
                    const float fg = 1.f / (1.f + __expf(-(pre[1] + gB1)));
                    const float gt = tanhf(pre[2] + gB2);
                    const float og = 1.f / (1.f + __expf(-(pre[3] + gB3)));
                    cB = fg * cB + ig * gt;
                    hvB = og * tanhf(cB);
                }
                const bool last = role ? (s == SEQ) : (s == SEQ - 1);
                if (last) {
                    h_tail[role * 16384 + lb * HIDDEN + j0 + hi4] = hvA;
                    h_tail[role * 16384 + lb * HIDDEN + j0 + 4 + hi4] = hvB;
                    c_tail[role * 16384 + lb * HIDDEN + j0 + hi4] = cA;
                    c_tail[role * 16384 + lb * HIDDEN + j0 + 4 + hi4] = cB;
                }
                // publish h to seq buffer (slot s+1 for L0, slot s for L1)
                const int wslot = role ? s : s + 1;
                u16* sq = role ? seq1 : seq0;
                float xA0 = __shfl(hvA, l), xA1 = __shfl(hvA, 16 + l);
                float xA2 = __shfl(hvA, 32 + l), xA3 = __shfl(hvA, 48 + l);
                float xB0 = __shfl(hvB, l), xB1 = __shfl(hvB, 16 + l);
                float xB2 = __shfl(hvB, 32 + l), xB3 = __shfl(hvB, 48 + l);
                if (l < 16) {
                    u32 hA0 = f2bf(xA0), hA1 = f2bf(xA1), hA2 = f2bf(xA2), hA3 = f2bf(xA3);
                    u64 hq0 = (u64)(hA0 | (hA1 << 16)) | ((u64)(hA2 | (hA3 << 16)) << 32);
                    u32 lA0 = f2bf(xA0 - bf2f(hA0)), lA1 = f2bf(xA1 - bf2f(hA1));
                    u32 lA2 = f2bf(xA2 - bf2f(hA2)), lA3 = f2bf(xA3 - bf2f(hA3));
                    u64 lq0 = (u64)(lA0 | (lA1 << 16)) | ((u64)(lA2 | (lA3 << 16)) << 32);
                    u32 hB0 = f2bf(xB0), hB1 = f2bf(xB1), hB2 = f2bf(xB2), hB3 = f2bf(xB3);
                    u64 hq1 = (u64)(hB0 | (hB1 << 16)) | ((u64)(hB2 | (hB3 << 16)) << 32);
                    u32 lB0 = f2bf(xB0 - bf2f(hB0)), lB1 = f2bf(xB1 - bf2f(hB1));
                    u32 lB2 = f2bf(xB2 - bf2f(hB2)), lB3 = f2bf(xB3 - bf2f(hB3));
                    u64 lq1 = (u64)(lB0 | (lB1 << 16)) | ((u64)(lB2 | (lB3 << 16)) << 32);
                    u64* dh = (u64*)sq;
                    u64* dl = (u64*)(sq + SEQ_LOU16);
                    const int iq = wslot * 4096 + l * 256 + (j0 >> 2);
                    astore(dh + iq, hq0);
                    astore(dl + iq, lq0);
                    astore(dh + iq + 1, hq1);
                    astore(dl + iq + 1, lq1);
                }
            }
        }
        if (s < SEQ) {
            if (tid < 64) {
                asm volatile("s_waitcnt vmcnt(0)" ::: "memory");  // drain publish
                if (tid == 0)
                    __hip_atomic_store(&arrive[bid], (u32)(s + 1), __ATOMIC_RELAXED,
                                       __HIP_MEMORY_SCOPE_AGENT);
                // off critical path: L0 prefetches next step's G0 gates
                if (role == 0 && s + 1 < SEQ) {
                    const float* gp = G0 + (size_t)((s + 1) * BATCH + lb) * GATES + j0;
                    gA0 = gp[hi4];              gB0 = gp[4 + hi4];
                    gA1 = gp[HIDDEN + hi4];     gB1 = gp[HIDDEN + 4 + hi4];
                    gA2 = gp[2 * HIDDEN + hi4]; gB2 = gp[2 * HIDDEN + 4 + hi4];
                    gA3 = gp[3 * HIDDEN + hi4]; gB3 = gp[3 * HIDDEN + 4 + hi4];
                }
                const u32 epoch = (u32)(s + 1);
                const int i0 = l * 4;
                for (;;) {
                    u32 q0 = __hip_atomic_load(&arrive[i0 + 0], __ATOMIC_RELAXED,
                                               __HIP_MEMORY_SCOPE_AGENT);
                    u32 q1 = __hip_atomic_load(&arrive[i0 + 1], __ATOMIC_RELAXED,
                                               __HIP_MEMORY_SCOPE_AGENT);
                    u32 q2 = __hip_atomic_load(&arrive[i0 + 2], __ATOMIC_RELAXED,
                                               __HIP_MEMORY_SCOPE_AGENT);
                    u32 q3 = __hip_atomic_load(&arrive[i0 + 3], __ATOMIC_RELAXED,
                                               __HIP_MEMORY_SCOPE_AGENT);
                    u32 m01 = q0 < q1 ? q0 : q1;
                    u32 m23 = q2 < q3 ? q2 : q3;
                    u32 mn = m01 < m23 ? m01 : m23;
                    if (__all(mn >= epoch)) break;
                    __builtin_amdgcn_s_sleep(2);
                }
                asm volatile("" ::: "memory");   // compiler barrier only
            }
            __syncthreads();
        }
    }
}

// ---------------- init & tails ----------------
__global__ void init_state(const float* __restrict__ h0, u16* __restrict__ seq0,
                           u16* __restrict__ seq1, u32* __restrict__ arrive) {
    int gid = blockIdx.x * 256 + threadIdx.x;  // 32768 = 2*16*1024
    if (gid < 256) arrive[gid] = 0;
    int layer = gid >> 14, b = (gid >> 10) & 15, j = gid & 1023;
    float h = h0[gid];
    u32 hb = f2bf(h);
    u32 lbits = f2bf(h - bf2f(hb));
    u16* sq = layer ? seq1 : seq0;
    sq[b * 1024 + j] = (u16)hb;               // slot 0 hi
    sq[SEQ_LOU16 + b * 1024 + j] = (u16)lbits; // slot 0 lo
}

__global__ void write_tails(const float* __restrict__ h_tail, const float* __restrict__ c_tail,
                            float* __restrict__ out) {
    int gid = blockIdx.x * 256 + threadIdx.x;  // 32768
    out[LOGITS_SZ + gid] = h_tail[gid];
    out[LOGITS_SZ + 32768 + gid] = c_tail[gid];
}

// ---------------- launch ----------------
extern "C" void kernel_launch(void* const* d_in, const int* in_sizes, int n_in,
                              void* d_out, int out_size, void* d_ws, size_t ws_size,
                              hipStream_t stream) {
    const int* x = (const int*)d_in[0];
    const float* h0 = (const float*)d_in[1];
    const float* c0 = (const float*)d_in[2];
    const float* emb = (const float*)d_in[3];
    const float* W_ih0 = (const float*)d_in[4];
    const float* W_hh0 = (const float*)d_in[5];
    const float* b_ih0 = (const float*)d_in[6];
    const float* b_hh0 = (const float*)d_in[7];
    const float* W_ih1 = (const float*)d_in[8];
    const float* W_hh1 = (const float*)d_in[9];
    const float* b_ih1 = (const float*)d_in[10];
    const float* b_hh1 = (const float*)d_in[11];
    const float* fc_W = (const float*)d_in[12];
    const float* fc_b = (const float*)d_in[13];
    float* out = (float*)d_out;
    float* ws = (float*)d_ws;

    // workspace layout (float offsets)
    const size_t OFF_G = 0;                                   // 16,777,216 (G0; later fc_W bf16)
    const size_t OFF_X0 = OFF_G + (size_t)MROWS * GATES;      // 2,097,152
    const size_t OFF_SEQ0 = OFF_X0 + (size_t)MROWS * EMBED;   // 4,210,688 (hi+lo u16)
    const size_t SEQ_FLOATS = (size_t)2 * NSLOT * SEQ_SLOTU16 / 2;
    const size_t OFF_SEQ1 = OFF_SEQ0 + SEQ_FLOATS;
    const size_t OFF_WIHH = OFF_SEQ1 + SEQ_FLOATS;            // 2,097,152
    const size_t OFF_WIHL = OFF_WIHH + (size_t)GATES * HIDDEN / 2;
    const size_t OFF_HT = OFF_WIHL + (size_t)GATES * HIDDEN / 2;  // 32768
    const size_t OFF_CT = OFF_HT + 2 * BATCH * HIDDEN;            // 32768
    const size_t OFF_AR = OFF_CT + 2 * BATCH * HIDDEN;            // 64

    u16* seq0 = (u16*)(ws + OFF_SEQ0);
    u16* seq1 = (u16*)(ws + OFF_SEQ1);
    u16* wihH = (u16*)(ws + OFF_WIHH);
    u16* wihL = (u16*)(ws + OFF_WIHL);
    u32* arrive = (u32*)(ws + OFF_AR);

    init_state<<<128, 256, 0, stream>>>(h0, seq0, seq1, arrive);
    embed_kernel<<<MROWS, 128, 0, stream>>>(x, emb, ws + OFF_X0);
    f32_to_bf16hl_kernel<<<2048, 256, 0, stream>>>(W_ih1, wihH, wihL, GATES * HIDDEN / 4);

    // layer-0 input projection for all timesteps (includes both layer-0 biases)
    gemm_bt<<<dim3(GATES / 128, MROWS / 128), 256, 0, stream>>>(
        ws + OFF_X0, W_ih0, b_ih0, b_hh0, ws + OFF_G, MROWS, GATES, EMBED, 0);

    // fused pipelined recurrence (both layers)
    {
        const float* Whh0p = W_hh0;
        const float* Whh1p = W_hh1;
        const float* Gp = ws + OFF_G;
        const u16* wh = wihH;
        const u16* wl = wihL;
        const float* bi = b_ih1;
        const float* bh = b_hh1;
        const float* ci = c0;
        float* ct = ws + OFF_CT;
        float* ht = ws + OFF_HT;
        u16* s0 = seq0;
        u16* s1 = seq1;
        u32* ar = arrive;
        void* args[] = {(void*)&Whh0p, (void*)&Whh1p, (void*)&Gp, (void*)&wh,
                        (void*)&wl, (void*)&bi, (void*)&bh, (void*)&ci,
                        (void*)&ct, (void*)&ht, (void*)&s0, (void*)&s1, (void*)&ar};
        hipLaunchCooperativeKernel((void*)lstm_fused, dim3(256), dim3(256), args, 0, stream);
    }

    // FC via bf16 MFMA: A = o1seq hi (slots 1..256) directly; B = fc_W bf16 (G0 dead)
    f32_to_bf16_kernel<<<4096, 256, 0, stream>>>(fc_W, (u16*)(ws + OFF_G), VOCAB * HIDDEN / 8);
    fc_mfma<<<dim3(VOCAB / 128, MROWS / 128), 256, 0, stream>>>(
        seq1 + SEQ_SLOTU16, (const u16*)(ws + OFF_G), fc_b, out);

    write_tails<<<128, 256, 0, stream>>>(ws + OFF_HT, ws + OFF_CT, out);
}

// Round 8
// 4662.872 us; speedup vs baseline: 1.2731x; 1.2731x over previous
//
#include <hip/hip_runtime.h>
#include <hip/hip_bf16.h>
#include <cmath>

// Problem constants
#define BATCH 16
#define SEQ 256
#define EMBED 512
#define HIDDEN 1024
#define GATES 4096       // 4*HIDDEN
#define VOCAB 32000
#define MROWS 4096       // BATCH*SEQ
#define LOGITS_SZ 131072000  // 16*256*32000

#define NSLOT 257                    // h-history slots (init + 256 steps)
#define SEQ_SLOTU16 16384            // u16 per slot: 16 batch x 1024
#define SEQ_LOU16 (NSLOT * SEQ_SLOTU16)

typedef unsigned int u32;
typedef unsigned short u16;
typedef unsigned long long u64;
typedef __attribute__((ext_vector_type(8))) short bf16x8;
typedef __attribute__((ext_vector_type(4))) float f32x4;

#define AS1 __attribute__((address_space(1)))
#define AS3 __attribute__((address_space(3)))

// ---------------- helpers ----------------
__device__ __forceinline__ u32 f2bf(float f) {          // RNE fp32->bf16 (bits)
    u32 u = __float_as_uint(f);
    return (u + 0x7fffu + ((u >> 16) & 1u)) >> 16;
}
__device__ __forceinline__ float bf2f(u32 b) { return __uint_as_float(b << 16); }

__device__ __forceinline__ u64 aload(const u64* p) {
    return __hip_atomic_load(p, __ATOMIC_RELAXED, __HIP_MEMORY_SCOPE_AGENT);
}
__device__ __forceinline__ void astore(u64* p, u64 v) {
    __hip_atomic_store(p, v, __ATOMIC_RELAXED, __HIP_MEMORY_SCOPE_AGENT);
}

// ---------------- embedding gather ----------------
__global__ void embed_kernel(const int* __restrict__ x, const float* __restrict__ emb,
                             float* __restrict__ X0) {
    int r = blockIdx.x;            // r = s*16 + b
    int s = r >> 4, b = r & 15;
    int tok = x[b * SEQ + s];
    const float4* src = (const float4*)(emb + (size_t)tok * EMBED);
    float4* dst = (float4*)(X0 + (size_t)r * EMBED);
    for (int i = threadIdx.x; i < EMBED / 4; i += blockDim.x) dst[i] = src[i];
}

// ---------------- fp32 GEMM: C[M,N] = A[M,K] @ B[N,K]^T + b1 + b2 ----------------
__global__ __launch_bounds__(256) void gemm_bt(
    const float* __restrict__ A, const float* __restrict__ B,
    const float* __restrict__ b1, const float* __restrict__ b2,
    float* __restrict__ C, int M, int N, int K, int perm) {
    __shared__ float As[8][128];
    __shared__ float Bs[8][128];
    int tid = threadIdx.x;
    int bm = blockIdx.y, bn = blockIdx.x;
    int arow = tid >> 1;
    int ak4 = (tid & 1) * 4;
    const float* Ag = A + (size_t)(bm * 128 + arow) * K + ak4;
    const float* Bg = B + (size_t)(bn * 128 + arow) * K + ak4;
    int tx = tid & 15, ty = tid >> 4;

    float acc[8][8];
#pragma unroll
    for (int i = 0; i < 8; i++)
#pragma unroll
        for (int j = 0; j < 8; j++) acc[i][j] = 0.f;

    for (int k0 = 0; k0 < K; k0 += 8) {
        float4 a4 = *(const float4*)(Ag + k0);
        float4 b4 = *(const float4*)(Bg + k0);
        __syncthreads();
        As[ak4 + 0][arow] = a4.x; As[ak4 + 1][arow] = a4.y;
        As[ak4 + 2][arow] = a4.z; As[ak4 + 3][arow] = a4.w;
        Bs[ak4 + 0][arow] = b4.x; Bs[ak4 + 1][arow] = b4.y;
        Bs[ak4 + 2][arow] = b4.z; Bs[ak4 + 3][arow] = b4.w;
        __syncthreads();
#pragma unroll
        for (int k = 0; k < 8; k++) {
            float av[8], bv[8];
            *(float4*)(av + 0) = *(const float4*)&As[k][ty * 8 + 0];
            *(float4*)(av + 4) = *(const float4*)&As[k][ty * 8 + 4];
            *(float4*)(bv + 0) = *(const float4*)&Bs[k][tx * 8 + 0];
            *(float4*)(bv + 4) = *(const float4*)&Bs[k][tx * 8 + 4];
#pragma unroll
            for (int i = 0; i < 8; i++)
#pragma unroll
                for (int j = 0; j < 8; j++) acc[i][j] += av[i] * bv[j];
        }
    }

#pragma unroll
    for (int i = 0; i < 8; i++) {
        int r = bm * 128 + ty * 8 + i;
        int orow = perm ? ((r & 15) * SEQ + (r >> 4)) : r;
#pragma unroll
        for (int j = 0; j < 8; j += 4) {
            int c = bn * 128 + tx * 8 + j;
            float4 v;
            float bb0 = (b1 ? b1[c + 0] : 0.f) + (b2 ? b2[c + 0] : 0.f);
            float bb1 = (b1 ? b1[c + 1] : 0.f) + (b2 ? b2[c + 1] : 0.f);
            float bb2 = (b1 ? b1[c + 2] : 0.f) + (b2 ? b2[c + 2] : 0.f);
            float bb3 = (b1 ? b1[c + 3] : 0.f) + (b2 ? b2[c + 3] : 0.f);
            v.x = acc[i][j + 0] + bb0;
            v.y = acc[i][j + 1] + bb1;
            v.z = acc[i][j + 2] + bb2;
            v.w = acc[i][j + 3] + bb3;
            *(float4*)&C[(size_t)orow * N + c] = v;
        }
    }
}

// ---------------- fp32 -> bf16 conversion (hi only, for fc_W) ----------------
__global__ __launch_bounds__(256) void f32_to_bf16_kernel(
    const float* __restrict__ in, u16* __restrict__ out, int n8) {
    for (int i = blockIdx.x * 256 + threadIdx.x; i < n8; i += gridDim.x * 256) {
        float4 a = ((const float4*)in)[2 * (size_t)i + 0];
        float4 b = ((const float4*)in)[2 * (size_t)i + 1];
        uint4 o;
        o.x = f2bf(a.x) | (f2bf(a.y) << 16);
        o.y = f2bf(a.z) | (f2bf(a.w) << 16);
        o.z = f2bf(b.x) | (f2bf(b.y) << 16);
        o.w = f2bf(b.z) | (f2bf(b.w) << 16);
        ((uint4*)out)[i] = o;
    }
}

// ---------------- W_ih1 pre-swizzle into MFMA fragment order ----------------
// out entry e = bid*2048 + s32*64 + l  holds  A[row=l&15][k=s32*32+(l>>4)*8 .. +8]
// for block bid (gate cols c=0..15 -> nrow=(c>>2)*HIDDEN + bid*4 + (c&3)).
__global__ __launch_bounds__(256) void wih_swizzle_kernel(
    const float* __restrict__ W, u16* __restrict__ hi, u16* __restrict__ lo) {
    int bid = blockIdx.x, tid = threadIdx.x;
    int j0 = bid * 4;
#pragma unroll
    for (int i = 0; i < 8; i++) {
        int q = i * 256 + tid;           // 0..2047
        int s32 = q >> 6, l = q & 63;
        int row = l & 15, hi4 = l >> 4;
        int nrow = (row >> 2) * HIDDEN + j0 + (row & 3);
        int k = s32 * 32 + hi4 * 8;
        const float* src = W + (size_t)nrow * HIDDEN + k;
        u32 hw[4], lw[4];
#pragma unroll
        for (int e = 0; e < 4; e++) {
            float x0 = src[2 * e], x1 = src[2 * e + 1];
            u32 h0 = f2bf(x0), h1 = f2bf(x1);
            hw[e] = h0 | (h1 << 16);
            lw[e] = f2bf(x0 - bf2f(h0)) | (f2bf(x1 - bf2f(h1)) << 16);
        }
        size_t e0 = (size_t)bid * 2048 + q;
        ((uint4*)hi)[e0] = make_uint4(hw[0], hw[1], hw[2], hw[3]);
        ((uint4*)lo)[e0] = make_uint4(lw[0], lw[1], lw[2], lw[3]);
    }
}

// ---------------- bf16 MFMA FC GEMM ----------------
__global__ __launch_bounds__(256) void fc_mfma(
    const u16* __restrict__ Abf,   // [MROWS][1024] bf16
    const u16* __restrict__ Bbf,   // [VOCAB][1024] bf16
    const float* __restrict__ bias,
    float* __restrict__ C) {
    const int K = HIDDEN;
    const int N = VOCAB;
    __shared__ char smem[16384];
    char* As = smem;
    char* Bs = smem + 8192;

    int tid = threadIdx.x;
    int w = tid >> 6, l = tid & 63;
    int bn = blockIdx.x, bm = blockIdx.y;
    int wr = w >> 1, wc = w & 1;
    int lr = l & 15, lk = l >> 4;

    f32x4 acc[4][4];
#pragma unroll
    for (int m = 0; m < 4; m++)
#pragma unroll
        for (int n = 0; n < 4; n++) acc[m][n] = {0.f, 0.f, 0.f, 0.f};

    int srow = tid >> 2, skc = (tid & 3) * 8;
    const u16* ga0 = Abf + (size_t)(bm * 128 + srow) * K + skc;
    const u16* ga1 = Abf + (size_t)(bm * 128 + 64 + srow) * K + skc;
    const u16* gb0 = Bbf + (size_t)(bn * 128 + srow) * K + skc;
    const u16* gb1 = Bbf + (size_t)(bn * 128 + 64 + srow) * K + skc;
    char* la0 = As + w * 1024;
    char* la1 = As + 4096 + w * 1024;
    char* lb0 = Bs + w * 1024;
    char* lb1 = Bs + 4096 + w * 1024;

    int afo[4], bfo[4];
#pragma unroll
    for (int m = 0; m < 4; m++) afo[m] = (wr * 64 + m * 16 + lr) * 64 + lk * 16;
#pragma unroll
    for (int n = 0; n < 4; n++) bfo[n] = (wc * 64 + n * 16 + lr) * 64 + lk * 16;

    for (int k0 = 0; k0 < K; k0 += 32) {
        __syncthreads();
        __builtin_amdgcn_global_load_lds((const AS1 u32*)(const void*)(ga0 + k0),
                                         (AS3 u32*)(void*)la0, 16, 0, 0);
        __builtin_amdgcn_global_load_lds((const AS1 u32*)(const void*)(ga1 + k0),
                                         (AS3 u32*)(void*)la1, 16, 0, 0);
        __builtin_amdgcn_global_load_lds((const AS1 u32*)(const void*)(gb0 + k0),
                                         (AS3 u32*)(void*)lb0, 16, 0, 0);
        __builtin_amdgcn_global_load_lds((const AS1 u32*)(const void*)(gb1 + k0),
                                         (AS3 u32*)(void*)lb1, 16, 0, 0);
        __syncthreads();

        bf16x8 af[4], bfr[4];
#pragma unroll
        for (int m = 0; m < 4; m++) af[m] = *(const bf16x8*)(As + afo[m]);
#pragma unroll
        for (int n = 0; n < 4; n++) bfr[n] = *(const bf16x8*)(Bs + bfo[n]);
#pragma unroll
        for (int m = 0; m < 4; m++)
#pragma unroll
            for (int n = 0; n < 4; n++)
                acc[m][n] = __builtin_amdgcn_mfma_f32_16x16x32_bf16(
                    af[m], bfr[n], acc[m][n], 0, 0, 0);
    }

    int rbase = bm * 128 + wr * 64 + lk * 4;
    int cbase = bn * 128 + wc * 64 + lr;
#pragma unroll
    for (int m = 0; m < 4; m++) {
#pragma unroll
        for (int n = 0; n < 4; n++) {
            int c = cbase + n * 16;
            float bb = bias[c];
#pragma unroll
            for (int j = 0; j < 4; j++) {
                int r = rbase + m * 16 + j;
                int orow = (r & 15) * SEQ + (r >> 4);   // [B,S,V] layout
                C[(size_t)orow * N + c] = acc[m][n][j] + bb;
            }
        }
    }
}

// ---------------- fused balanced 2-layer persistent LSTM ----------------------
// 256 blocks x 256 threads. EVERY block owns 4 L0 units AND 4 L1 units (16 gate
// cols each). Step s: L0 computes t=s, L1 computes t=s-1; both consume seq0
// slot s (shared x fragments). Whh0/Whh1 hi/lo in LDS; W_ih1 streamed from L2
// in pre-swizzled fragment order (coalesced). One barrier per step.
__global__ __launch_bounds__(256) void lstm_fused(
    const float* __restrict__ Whh0, const float* __restrict__ Whh1,
    const float* __restrict__ G0,        // [4096][4096] rows t*16+b (L0 x-proj + biases)
    const u16* __restrict__ wih_hi,      // pre-swizzled [256][2048] x 16B
    const u16* __restrict__ wih_lo,
    const float* __restrict__ bi1, const float* __restrict__ bh1,
    const float* __restrict__ c0in,      // [2][16][1024]
    float* __restrict__ c_tail, float* __restrict__ h_tail,  // [2][16][1024]
    u16* __restrict__ seq0, u16* __restrict__ seq1,          // [NSLOT hi | NSLOT lo]
    u32* __restrict__ arrive) {
    __shared__ __align__(16) char lds[139264];
    char* W0hi = lds;                   // [16 rows][2048B] swizzled Whh0 hi
    char* W0lo = lds + 32768;
    char* W1hi = lds + 65536;
    char* W1lo = lds + 98304;
    float* Pw = (float*)(lds + 131072); // [2 layer][4 wave][64 lane][4] = 8 KB

    const int tid = threadIdx.x;
    const int bid = blockIdx.x;
    const int j0 = bid * 4;                  // 4 units per layer per block
    const int w = tid >> 6, l = tid & 63;
    const int lb = l & 15, hi4 = l >> 4, xr = l & 7;

    // ---- one-time: stage Whh0/Whh1 slices (16 gate-cols x 1024) hi/lo ----
#pragma unroll
    for (int lay = 0; lay < 2; lay++) {
        const float* Whh = lay ? Whh1 : Whh0;
        char* dH = lay ? W1hi : W0hi;
        char* dL = lay ? W1lo : W0lo;
        for (int i = 0; i < 8; i++) {
            int q = i * 256 + tid;            // 16B chunk id 0..2047
            int row = q >> 7, cin = q & 127;  // row = gate-col (0..15)
            int nrow = (row >> 2) * HIDDEN + j0 + (row & 3);
            const float* src = Whh + (size_t)nrow * HIDDEN + cin * 8;
            int dst = row * 2048 + ((cin ^ (row & 7)) << 4);
            u32 hw[4], lw[4];
#pragma unroll
            for (int e = 0; e < 4; e++) {
                float x0 = src[2 * e], x1 = src[2 * e + 1];
                u32 hb0 = f2bf(x0), hb1 = f2bf(x1);
                hw[e] = hb0 | (hb1 << 16);
                lw[e] = f2bf(x0 - bf2f(hb0)) | (f2bf(x1 - bf2f(hb1)) << 16);
            }
            *(uint4*)(dH + dst) = make_uint4(hw[0], hw[1], hw[2], hw[3]);
            *(uint4*)(dL + dst) = make_uint4(lw[0], lw[1], lw[2], lw[3]);
        }
    }

    // pointwise state (wave 0): lane l -> batch lb, unit jj = hi4 (one per layer)
    float c0r = 0.f, c1r = 0.f;
    float g00 = 0, g01 = 0, g02 = 0, g03 = 0;   // L0 gates (prefetched from G0)
    float g10 = 0, g11 = 0, g12 = 0, g13 = 0;   // L1 gates (constant biases)
    if (tid < 64) {
        c0r = c0in[lb * HIDDEN + j0 + hi4];
        c1r = c0in[16384 + lb * HIDDEN + j0 + hi4];
        const float* gp = G0 + (size_t)lb * GATES + j0 + hi4;   // t = 0
        g00 = gp[0]; g01 = gp[HIDDEN]; g02 = gp[2 * HIDDEN]; g03 = gp[3 * HIDDEN];
        g10 = bi1[j0 + hi4] + bh1[j0 + hi4];
        g11 = bi1[HIDDEN + j0 + hi4] + bh1[HIDDEN + j0 + hi4];
        g12 = bi1[2 * HIDDEN + j0 + hi4] + bh1[2 * HIDDEN + j0 + hi4];
        g13 = bi1[3 * HIDDEN + j0 + hi4] + bh1[3 * HIDDEN + j0 + hi4];
    }
    __syncthreads();

    const u64* s0h = (const u64*)seq0;
    const u64* s0l = (const u64*)(seq0 + SEQ_LOU16);
    const u64* s1h = (const u64*)seq1;
    const u64* s1l = (const u64*)(seq1 + SEQ_LOU16);
    const int fb = lb * 256 + hi4 * 2;            // u64 base within a slot
    const size_t wbase = (size_t)bid * 2048 + l;  // wih fragment entry base

    for (int s = 0; s <= SEQ; s++) {
        const bool actL0 = (s < SEQ);
        const bool actL1 = (s >= 1);

        // ---- x fragments: seq0 slot s (L0 B-operand AND L1 inproj B-operand) ----
        u64 xh[16], xl[16];
        {
            const int base = s * 4096 + fb;
#pragma unroll
            for (int ss = 0; ss < 8; ss++) {
                const int idx = base + (w * 8 + ss) * 8;
                xh[2 * ss + 0] = aload(s0h + idx + 0);
                xh[2 * ss + 1] = aload(s0h + idx + 1);
                xl[2 * ss + 0] = aload(s0l + idx + 0);
                xl[2 * ss + 1] = aload(s0l + idx + 1);
            }
        }

        if (actL0) {
            f32x4 a0 = {0.f,0.f,0.f,0.f}, a1 = {0.f,0.f,0.f,0.f}, a2 = {0.f,0.f,0.f,0.f};
#pragma unroll
            for (int ss = 0; ss < 8; ss++) {
                const int s32 = w * 8 + ss;
                const int off = lb * 2048 + (((s32 * 4 + hi4) ^ xr) << 4);
                union { u64 q[2]; bf16x8 v; } bh_, bl_;
                bh_.q[0] = xh[2 * ss]; bh_.q[1] = xh[2 * ss + 1];
                bl_.q[0] = xl[2 * ss]; bl_.q[1] = xl[2 * ss + 1];
                bf16x8 ah = *(const bf16x8*)(W0hi + off);
                bf16x8 al = *(const bf16x8*)(W0lo + off);
                a0 = __builtin_amdgcn_mfma_f32_16x16x32_bf16(ah, bh_.v, a0, 0, 0, 0);
                a1 = __builtin_amdgcn_mfma_f32_16x16x32_bf16(al, bh_.v, a1, 0, 0, 0);
                a2 = __builtin_amdgcn_mfma_f32_16x16x32_bf16(ah, bl_.v, a2, 0, 0, 0);
            }
            f32x4 v0 = a0 + a1 + a2;
            *(f32x4*)&Pw[((0 * 4 + w) * 64 + l) * 4] = v0;
        }

        if (actL1) {
            // y fragments: seq1 slot s-1 (h1 state)
            u64 yh[16], yl[16];
            {
                const int base = (s - 1) * 4096 + fb;
#pragma unroll
                for (int ss = 0; ss < 8; ss++) {
                    const int idx = base + (w * 8 + ss) * 8;
                    yh[2 * ss + 0] = aload(s1h + idx + 0);
                    yh[2 * ss + 1] = aload(s1h + idx + 1);
                    yl[2 * ss + 0] = aload(s1l + idx + 0);
                    yl[2 * ss + 1] = aload(s1l + idx + 1);
                }
            }
            f32x4 a0 = {0.f,0.f,0.f,0.f}, a1 = {0.f,0.f,0.f,0.f}, a2 = {0.f,0.f,0.f,0.f};
            // input projection: A = pre-swizzled wih frags (coalesced L2 stream)
#pragma unroll
            for (int ss = 0; ss < 8; ss++) {
                const size_t e = wbase + (size_t)(w * 8 + ss) * 64;
                union { u64 q[2]; bf16x8 v; } bh_, bl_;
                bh_.q[0] = xh[2 * ss]; bh_.q[1] = xh[2 * ss + 1];
                bl_.q[0] = xl[2 * ss]; bl_.q[1] = xl[2 * ss + 1];
                bf16x8 ah = *(const bf16x8*)(wih_hi + e * 8);
                bf16x8 al = *(const bf16x8*)(wih_lo + e * 8);
                a0 = __builtin_amdgcn_mfma_f32_16x16x32_bf16(ah, bh_.v, a0, 0, 0, 0);
                a1 = __builtin_amdgcn_mfma_f32_16x16x32_bf16(al, bh_.v, a1, 0, 0, 0);
                a2 = __builtin_amdgcn_mfma_f32_16x16x32_bf16(ah, bl_.v, a2, 0, 0, 0);
            }
            // recurrent: A = LDS Whh1
#pragma unroll
            for (int ss = 0; ss < 8; ss++) {
                const int s32 = w * 8 + ss;
                const int off = lb * 2048 + (((s32 * 4 + hi4) ^ xr) << 4);
                union { u64 q[2]; bf16x8 v; } bh_, bl_;
                bh_.q[0] = yh[2 * ss]; bh_.q[1] = yh[2 * ss + 1];
                bl_.q[0] = yl[2 * ss]; bl_.q[1] = yl[2 * ss + 1];
                bf16x8 ah = *(const bf16x8*)(W1hi + off);
                bf16x8 al = *(const bf16x8*)(W1lo + off);
                a0 = __builtin_amdgcn_mfma_f32_16x16x32_bf16(ah, bh_.v, a0, 0, 0, 0);
                a1 = __builtin_amdgcn_mfma_f32_16x16x32_bf16(al, bh_.v, a1, 0, 0, 0);
                a2 = __builtin_amdgcn_mfma_f32_16x16x32_bf16(ah, bl_.v, a2, 0, 0, 0);
            }
            f32x4 v1 = a0 + a1 + a2;
            *(f32x4*)&Pw[((1 * 4 + w) * 64 + l) * 4] = v1;
        }
        __syncthreads();

        if (tid < 64) {
            // D layout: Pw[(lay*4+w)*64 + ll][jw] = D[c=(ll>>4)*4+jw][b=ll&15].
            // lane handles unit jj=hi4: gate g -> c=g*4+hi4 -> ll=(g<<4)|lb, jw=hi4.
            if (actL0) {
                float pre[4];
#pragma unroll
                for (int g = 0; g < 4; g++) {
                    const int ll = (g << 4) | lb;
                    pre[g] = Pw[((0 * 4 + 0) * 64 + ll) * 4 + hi4]
                           + Pw[((0 * 4 + 1) * 64 + ll) * 4 + hi4]
                           + Pw[((0 * 4 + 2) * 64 + ll) * 4 + hi4]
                           + Pw[((0 * 4 + 3) * 64 + ll) * 4 + hi4];
                }
                const float ig = 1.f / (1.f + __expf(-(pre[0] + g00)));
                const float fg = 1.f / (1.f + __expf(-(pre[1] + g01)));
                const float gt = tanhf(pre[2] + g02);
                const float og = 1.f / (1.f + __expf(-(pre[3] + g03)));
                c0r = fg * c0r + ig * gt;
                const float hv = og * tanhf(c0r);
                if (s == SEQ - 1) {
                    h_tail[lb * HIDDEN + j0 + hi4] = hv;
                    c_tail[lb * HIDDEN + j0 + hi4] = c0r;
                }
                // publish o0[t=s] to seq0 slot s+1
                float q0 = __shfl(hv, 0 + l), q1 = __shfl(hv, 16 + l);
                float q2 = __shfl(hv, 32 + l), q3 = __shfl(hv, 48 + l);
                if (l < 16) {
                    u32 hb0 = f2bf(q0), hb1 = f2bf(q1), hb2 = f2bf(q2), hb3 = f2bf(q3);
                    u64 hq = (u64)(hb0 | (hb1 << 16)) | ((u64)(hb2 | (hb3 << 16)) << 32);
                    u32 lb0 = f2bf(q0 - bf2f(hb0)), lb1 = f2bf(q1 - bf2f(hb1));
                    u32 lb2 = f2bf(q2 - bf2f(hb2)), lb3 = f2bf(q3 - bf2f(hb3));
                    u64 lq = (u64)(lb0 | (lb1 << 16)) | ((u64)(lb2 | (lb3 << 16)) << 32);
                    const int iq = (s + 1) * 4096 + l * 256 + bid;
                    astore((u64*)seq0 + iq, hq);
                    astore((u64*)(seq0 + SEQ_LOU16) + iq, lq);
                }
            }
            if (actL1) {
                float pre[4];
#pragma unroll
                for (int g = 0; g < 4; g++) {
                    const int ll = (g << 4) | lb;
                    pre[g] = Pw[((1 * 4 + 0) * 64 + ll) * 4 + hi4]
                           + Pw[((1 * 4 + 1) * 64 + ll) * 4 + hi4]
                           + Pw[((1 * 4 + 2) * 64 + ll) * 4 + hi4]
                           + Pw[((1 * 4 + 3) * 64 + ll) * 4 + hi4];
                }
                const float ig = 1.f / (1.f + __expf(-(pre[0] + g10)));
                const float fg = 1.f / (1.f + __expf(-(pre[1] + g11)));
                const float gt = tanhf(pre[2] + g12);
                const float og = 1.f / (1.f + __expf(-(pre[3] + g13)));
                c1r = fg * c1r + ig * gt;
                const float hv = og * tanhf(c1r);
                if (s == SEQ) {
                    h_tail[16384 + lb * HIDDEN + j0 + hi4] = hv;
                    c_tail[16384 + lb * HIDDEN + j0 + hi4] = c1r;
                }
                // publish o1[t=s-1] to seq1 slot s
                float q0 = __shfl(hv, 0 + l), q1 = __shfl(hv, 16 + l);
                float q2 = __shfl(hv, 32 + l), q3 = __shfl(hv, 48 + l);
                if (l < 16) {
                    u32 hb0 = f2bf(q0), hb1 = f2bf(q1), hb2 = f2bf(q2), hb3 = f2bf(q3);
                    u64 hq = (u64)(hb0 | (hb1 << 16)) | ((u64)(hb2 | (hb3 << 16)) << 32);
                    u32 lb0 = f2bf(q0 - bf2f(hb0)), lb1 = f2bf(q1 - bf2f(hb1));
                    u32 lb2 = f2bf(q2 - bf2f(hb2)), lb3 = f2bf(q3 - bf2f(hb3));
                    u64 lq = (u64)(lb0 | (lb1 << 16)) | ((u64)(lb2 | (lb3 << 16)) << 32);
                    const int iq = s * 4096 + l * 256 + bid;
                    astore((u64*)seq1 + iq, hq);
                    astore((u64*)(seq1 + SEQ_LOU16) + iq, lq);
                }
            }
        }

        if (s < SEQ) {
            if (tid < 64) {
                asm volatile("s_waitcnt vmcnt(0)" ::: "memory");  // drain publishes
                if (tid == 0)
                    __hip_atomic_store(&arrive[bid], (u32)(s + 1), __ATOMIC_RELAXED,
                                       __HIP_MEMORY_SCOPE_AGENT);
                // off critical path: prefetch next step's G0 gates
                if (s + 1 < SEQ) {
                    const float* gp = G0 + (size_t)((s + 1) * BATCH + lb) * GATES + j0 + hi4;
                    g00 = gp[0]; g01 = gp[HIDDEN];
                    g02 = gp[2 * HIDDEN]; g03 = gp[3 * HIDDEN];
                }
                const u32 epoch = (u32)(s + 1);
                const int i0 = l * 4;
                for (;;) {
                    u32 q0 = __hip_atomic_load(&arrive[i0 + 0], __ATOMIC_RELAXED,
                                               __HIP_MEMORY_SCOPE_AGENT);
                    u32 q1 = __hip_atomic_load(&arrive[i0 + 1], __ATOMIC_RELAXED,
                                               __HIP_MEMORY_SCOPE_AGENT);
                    u32 q2 = __hip_atomic_load(&arrive[i0 + 2], __ATOMIC_RELAXED,
                                               __HIP_MEMORY_SCOPE_AGENT);
                    u32 q3 = __hip_atomic_load(&arrive[i0 + 3], __ATOMIC_RELAXED,
                                               __HIP_MEMORY_SCOPE_AGENT);
                    u32 m01 = q0 < q1 ? q0 : q1;
                    u32 m23 = q2 < q3 ? q2 : q3;
                    u32 mn = m01 < m23 ? m01 : m23;
                    if (__all(mn >= epoch)) break;
                    __builtin_amdgcn_s_sleep(2);
                }
                asm volatile("" ::: "memory");   // compiler barrier only
            }
            __syncthreads();
        }
    }
}

// ---------------- init & tails ----------------
__global__ void init_state(const float* __restrict__ h0, u16* __restrict__ seq0,
                           u16* __restrict__ seq1, u32* __restrict__ arrive) {
    int gid = blockIdx.x * 256 + threadIdx.x;  // 32768 = 2*16*1024
    if (gid < 256) arrive[gid] = 0;
    int layer = gid >> 14, b = (gid >> 10) & 15, j = gid & 1023;
    float h = h0[gid];
    u32 hb = f2bf(h);
    u32 lbits = f2bf(h - bf2f(hb));
    u16* sq = layer ? seq1 : seq0;
    sq[b * 1024 + j] = (u16)hb;                 // slot 0 hi
    sq[SEQ_LOU16 + b * 1024 + j] = (u16)lbits;  // slot 0 lo
}

__global__ void write_tails(const float* __restrict__ h_tail, const float* __restrict__ c_tail,
                            float* __restrict__ out) {
    int gid = blockIdx.x * 256 + threadIdx.x;  // 32768
    out[LOGITS_SZ + gid] = h_tail[gid];
    out[LOGITS_SZ + 32768 + gid] = c_tail[gid];
}

// ---------------- launch ----------------
extern "C" void kernel_launch(void* const* d_in, const int* in_sizes, int n_in,
                              void* d_out, int out_size, void* d_ws, size_t ws_size,
                              hipStream_t stream) {
    const int* x = (const int*)d_in[0];
    const float* h0 = (const float*)d_in[1];
    const float* c0 = (const float*)d_in[2];
    const float* emb = (const float*)d_in[3];
    const float* W_ih0 = (const float*)d_in[4];
    const float* W_hh0 = (const float*)d_in[5];
    const float* b_ih0 = (const float*)d_in[6];
    const float* b_hh0 = (const float*)d_in[7];
    const float* W_ih1 = (const float*)d_in[8];
    const float* W_hh1 = (const float*)d_in[9];
    const float* b_ih1 = (const float*)d_in[10];
    const float* b_hh1 = (const float*)d_in[11];
    const float* fc_W = (const float*)d_in[12];
    const float* fc_b = (const float*)d_in[13];
    float* out = (float*)d_out;
    float* ws = (float*)d_ws;

    // workspace layout (float offsets)
    const size_t OFF_G = 0;                                   // G0; later fc_W bf16
    const size_t OFF_X0 = OFF_G + (size_t)MROWS * GATES;
    const size_t OFF_SEQ0 = OFF_X0 + (size_t)MROWS * EMBED;
    const size_t SEQ_FLOATS = (size_t)2 * NSLOT * SEQ_SLOTU16 / 2;
    const size_t OFF_SEQ1 = OFF_SEQ0 + SEQ_FLOATS;
    const size_t OFF_WIHH = OFF_SEQ1 + SEQ_FLOATS;
    const size_t OFF_WIHL = OFF_WIHH + (size_t)GATES * HIDDEN / 2;
    const size_t OFF_HT = OFF_WIHL + (size_t)GATES * HIDDEN / 2;
    const size_t OFF_CT = OFF_HT + 2 * BATCH * HIDDEN;
    const size_t OFF_AR = OFF_CT + 2 * BATCH * HIDDEN;

    u16* seq0 = (u16*)(ws + OFF_SEQ0);
    u16* seq1 = (u16*)(ws + OFF_SEQ1);
    u16* wihH = (u16*)(ws + OFF_WIHH);
    u16* wihL = (u16*)(ws + OFF_WIHL);
    u32* arrive = (u32*)(ws + OFF_AR);

    init_state<<<128, 256, 0, stream>>>(h0, seq0, seq1, arrive);
    embed_kernel<<<MROWS, 128, 0, stream>>>(x, emb, ws + OFF_X0);
    wih_swizzle_kernel<<<256, 256, 0, stream>>>(W_ih1, wihH, wihL);

    // layer-0 input projection for all timesteps (includes both layer-0 biases)
    gemm_bt<<<dim3(GATES / 128, MROWS / 128), 256, 0, stream>>>(
        ws + OFF_X0, W_ih0, b_ih0, b_hh0, ws + OFF_G, MROWS, GATES, EMBED, 0);

    // fused balanced pipelined recurrence (both layers)
    {
        const float* Whh0p = W_hh0;
        const float* Whh1p = W_hh1;
        const float* Gp = ws + OFF_G;
        const u16* wh = wihH;
        const u16* wl = wihL;
        const float* bi = b_ih1;
        const float* bh = b_hh1;
        const float* ci = c0;
        float* ct = ws + OFF_CT;
        float* ht = ws + OFF_HT;
        u16* s0 = seq0;
        u16* s1 = seq1;
        u32* ar = arrive;
        void* args[] = {(void*)&Whh0p, (void*)&Whh1p, (void*)&Gp, (void*)&wh,
                        (void*)&wl, (void*)&bi, (void*)&bh, (void*)&ci,
                        (void*)&ct, (void*)&ht, (void*)&s0, (void*)&s1, (void*)&ar};
        hipLaunchCooperativeKernel((void*)lstm_fused, dim3(256), dim3(256), args, 0, stream);
    }

    // FC via bf16 MFMA: A = seq1 hi slots 1..256 directly; B = fc_W bf16 (G0 dead)
    f32_to_bf16_kernel<<<4096, 256, 0, stream>>>(fc_W, (u16*)(ws + OFF_G), VOCAB * HIDDEN / 8);
    fc_mfma<<<dim3(VOCAB / 128, MROWS / 128), 256, 0, stream>>>(
        seq1 + SEQ_SLOTU16, (const u16*)(ws + OFF_G), fc_b, out);

    write_tails<<<128, 256, 0, stream>>>(ws + OFF_HT, ws + OFF_CT, out);
}

// Round 9
// 4015.178 us; speedup vs baseline: 1.4785x; 1.1613x over previous
//
#include <hip/hip_runtime.h>
#include <hip/hip_bf16.h>
#include <cmath>

// Problem constants
#define BATCH 16
#define SEQ 256
#define EMBED 512
#define HIDDEN 1024
#define GATES 4096       // 4*HIDDEN
#define VOCAB 32000
#define MROWS 4096       // BATCH*SEQ
#define LOGITS_SZ 131072000  // 16*256*32000

#define NSLOT 257                    // h-history slots (init + 256 steps)
#define SEQ_SLOTU16 16384            // u16 per slot: 16 batch x 1024
#define SEQ_LOU16 (NSLOT * SEQ_SLOTU16)

typedef unsigned int u32;
typedef unsigned short u16;
typedef unsigned long long u64;
typedef __attribute__((ext_vector_type(8))) short bf16x8;
typedef __attribute__((ext_vector_type(4))) float f32x4;

#define AS1 __attribute__((address_space(1)))
#define AS3 __attribute__((address_space(3)))

// ---------------- helpers ----------------
__device__ __forceinline__ u32 f2bf(float f) {          // RNE fp32->bf16 (bits)
    u32 u = __float_as_uint(f);
    return (u + 0x7fffu + ((u >> 16) & 1u)) >> 16;
}
__device__ __forceinline__ float bf2f(u32 b) { return __uint_as_float(b << 16); }

__device__ __forceinline__ void astore(u64* p, u64 v) {
    __hip_atomic_store(p, v, __ATOMIC_RELAXED, __HIP_MEMORY_SCOPE_AGENT);
}

// ---------------- embedding gather ----------------
__global__ void embed_kernel(const int* __restrict__ x, const float* __restrict__ emb,
                             float* __restrict__ X0) {
    int r = blockIdx.x;            // r = s*16 + b
    int s = r >> 4, b = r & 15;
    int tok = x[b * SEQ + s];
    const float4* src = (const float4*)(emb + (size_t)tok * EMBED);
    float4* dst = (float4*)(X0 + (size_t)r * EMBED);
    for (int i = threadIdx.x; i < EMBED / 4; i += blockDim.x) dst[i] = src[i];
}

// ---------------- fp32 GEMM: C[M,N] = A[M,K] @ B[N,K]^T + b1 + b2 ----------------
__global__ __launch_bounds__(256) void gemm_bt(
    const float* __restrict__ A, const float* __restrict__ B,
    const float* __restrict__ b1, const float* __restrict__ b2,
    float* __restrict__ C, int M, int N, int K, int perm) {
    __shared__ float As[8][128];
    __shared__ float Bs[8][128];
    int tid = threadIdx.x;
    int bm = blockIdx.y, bn = blockIdx.x;
    int arow = tid >> 1;
    int ak4 = (tid & 1) * 4;
    const float* Ag = A + (size_t)(bm * 128 + arow) * K + ak4;
    const float* Bg = B + (size_t)(bn * 128 + arow) * K + ak4;
    int tx = tid & 15, ty = tid >> 4;

    float acc[8][8];
#pragma unroll
    for (int i = 0; i < 8; i++)
#pragma unroll
        for (int j = 0; j < 8; j++) acc[i][j] = 0.f;

    for (int k0 = 0; k0 < K; k0 += 8) {
        float4 a4 = *(const float4*)(Ag + k0);
        float4 b4 = *(const float4*)(Bg + k0);
        __syncthreads();
        As[ak4 + 0][arow] = a4.x; As[ak4 + 1][arow] = a4.y;
        As[ak4 + 2][arow] = a4.z; As[ak4 + 3][arow] = a4.w;
        Bs[ak4 + 0][arow] = b4.x; Bs[ak4 + 1][arow] = b4.y;
        Bs[ak4 + 2][arow] = b4.z; Bs[ak4 + 3][arow] = b4.w;
        __syncthreads();
#pragma unroll
        for (int k = 0; k < 8; k++) {
            float av[8], bv[8];
            *(float4*)(av + 0) = *(const float4*)&As[k][ty * 8 + 0];
            *(float4*)(av + 4) = *(const float4*)&As[k][ty * 8 + 4];
            *(float4*)(bv + 0) = *(const float4*)&Bs[k][tx * 8 + 0];
            *(float4*)(bv + 4) = *(const float4*)&Bs[k][tx * 8 + 4];
#pragma unroll
            for (int i = 0; i < 8; i++)
#pragma unroll
                for (int j = 0; j < 8; j++) acc[i][j] += av[i] * bv[j];
        }
    }

#pragma unroll
    for (int i = 0; i < 8; i++) {
        int r = bm * 128 + ty * 8 + i;
        int orow = perm ? ((r & 15) * SEQ + (r >> 4)) : r;
#pragma unroll
        for (int j = 0; j < 8; j += 4) {
            int c = bn * 128 + tx * 8 + j;
            float4 v;
            float bb0 = (b1 ? b1[c + 0] : 0.f) + (b2 ? b2[c + 0] : 0.f);
            float bb1 = (b1 ? b1[c + 1] : 0.f) + (b2 ? b2[c + 1] : 0.f);
            float bb2 = (b1 ? b1[c + 2] : 0.f) + (b2 ? b2[c + 2] : 0.f);
            float bb3 = (b1 ? b1[c + 3] : 0.f) + (b2 ? b2[c + 3] : 0.f);
            v.x = acc[i][j + 0] + bb0;
            v.y = acc[i][j + 1] + bb1;
            v.z = acc[i][j + 2] + bb2;
            v.w = acc[i][j + 3] + bb3;
            *(float4*)&C[(size_t)orow * N + c] = v;
        }
    }
}

// ---------------- fp32 -> bf16 conversion (hi only, for fc_W) ----------------
__global__ __launch_bounds__(256) void f32_to_bf16_kernel(
    const float* __restrict__ in, u16* __restrict__ out, int n8) {
    for (int i = blockIdx.x * 256 + threadIdx.x; i < n8; i += gridDim.x * 256) {
        float4 a = ((const float4*)in)[2 * (size_t)i + 0];
        float4 b = ((const float4*)in)[2 * (size_t)i + 1];
        uint4 o;
        o.x = f2bf(a.x) | (f2bf(a.y) << 16);
        o.y = f2bf(a.z) | (f2bf(a.w) << 16);
        o.z = f2bf(b.x) | (f2bf(b.y) << 16);
        o.w = f2bf(b.z) | (f2bf(b.w) << 16);
        ((uint4*)out)[i] = o;
    }
}

// ---------------- W_ih1 pre-swizzle into MFMA fragment order ----------------
// out entry e = bid*2048 + s32*64 + l  holds  A[row=l&15][k=s32*32+(l>>4)*8 .. +8]
// for block bid (gate cols c=0..15 -> nrow=(c>>2)*HIDDEN + bid*4 + (c&3)).
__global__ __launch_bounds__(256) void wih_swizzle_kernel(
    const float* __restrict__ W, u16* __restrict__ hi, u16* __restrict__ lo) {
    int bid = blockIdx.x, tid = threadIdx.x;
    int j0 = bid * 4;
#pragma unroll
    for (int i = 0; i < 8; i++) {
        int q = i * 256 + tid;           // 0..2047
        int s32 = q >> 6, l = q & 63;
        int row = l & 15, hi4 = l >> 4;
        int nrow = (row >> 2) * HIDDEN + j0 + (row & 3);
        int k = s32 * 32 + hi4 * 8;
        const float* src = W + (size_t)nrow * HIDDEN + k;
        u32 hw[4], lw[4];
#pragma unroll
        for (int e = 0; e < 4; e++) {
            float x0 = src[2 * e], x1 = src[2 * e + 1];
            u32 h0 = f2bf(x0), h1 = f2bf(x1);
            hw[e] = h0 | (h1 << 16);
            lw[e] = f2bf(x0 - bf2f(h0)) | (f2bf(x1 - bf2f(h1)) << 16);
        }
        size_t e0 = (size_t)bid * 2048 + q;
        ((uint4*)hi)[e0] = make_uint4(hw[0], hw[1], hw[2], hw[3]);
        ((uint4*)lo)[e0] = make_uint4(lw[0], lw[1], lw[2], lw[3]);
    }
}

// ---------------- bf16 MFMA FC GEMM ----------------
__global__ __launch_bounds__(256) void fc_mfma(
    const u16* __restrict__ Abf,   // [MROWS][1024] bf16
    const u16* __restrict__ Bbf,   // [VOCAB][1024] bf16
    const float* __restrict__ bias,
    float* __restrict__ C) {
    const int K = HIDDEN;
    const int N = VOCAB;
    __shared__ char smem[16384];
    char* As = smem;
    char* Bs = smem + 8192;

    int tid = threadIdx.x;
    int w = tid >> 6, l = tid & 63;
    int bn = blockIdx.x, bm = blockIdx.y;
    int wr = w >> 1, wc = w & 1;
    int lr = l & 15, lk = l >> 4;

    f32x4 acc[4][4];
#pragma unroll
    for (int m = 0; m < 4; m++)
#pragma unroll
        for (int n = 0; n < 4; n++) acc[m][n] = {0.f, 0.f, 0.f, 0.f};

    int srow = tid >> 2, skc = (tid & 3) * 8;
    const u16* ga0 = Abf + (size_t)(bm * 128 + srow) * K + skc;
    const u16* ga1 = Abf + (size_t)(bm * 128 + 64 + srow) * K + skc;
    const u16* gb0 = Bbf + (size_t)(bn * 128 + srow) * K + skc;
    const u16* gb1 = Bbf + (size_t)(bn * 128 + 64 + srow) * K + skc;
    char* la0 = As + w * 1024;
    char* la1 = As + 4096 + w * 1024;
    char* lb0 = Bs + w * 1024;
    char* lb1 = Bs + 4096 + w * 1024;

    int afo[4], bfo[4];
#pragma unroll
    for (int m = 0; m < 4; m++) afo[m] = (wr * 64 + m * 16 + lr) * 64 + lk * 16;
#pragma unroll
    for (int n = 0; n < 4; n++) bfo[n] = (wc * 64 + n * 16 + lr) * 64 + lk * 16;

    for (int k0 = 0; k0 < K; k0 += 32) {
        __syncthreads();
        __builtin_amdgcn_global_load_lds((const AS1 u32*)(const void*)(ga0 + k0),
                                         (AS3 u32*)(void*)la0, 16, 0, 0);
        __builtin_amdgcn_global_load_lds((const AS1 u32*)(const void*)(ga1 + k0),
                                         (AS3 u32*)(void*)la1, 16, 0, 0);
        __builtin_amdgcn_global_load_lds((const AS1 u32*)(const void*)(gb0 + k0),
                                         (AS3 u32*)(void*)lb0, 16, 0, 0);
        __builtin_amdgcn_global_load_lds((const AS1 u32*)(const void*)(gb1 + k0),
                                         (AS3 u32*)(void*)lb1, 16, 0, 0);
        __syncthreads();

        bf16x8 af[4], bfr[4];
#pragma unroll
        for (int m = 0; m < 4; m++) af[m] = *(const bf16x8*)(As + afo[m]);
#pragma unroll
        for (int n = 0; n < 4; n++) bfr[n] = *(const bf16x8*)(Bs + bfo[n]);
#pragma unroll
        for (int m = 0; m < 4; m++)
#pragma unroll
            for (int n = 0; n < 4; n++)
                acc[m][n] = __builtin_amdgcn_mfma_f32_16x16x32_bf16(
                    af[m], bfr[n], acc[m][n], 0, 0, 0);
    }

    int rbase = bm * 128 + wr * 64 + lk * 4;
    int cbase = bn * 128 + wc * 64 + lr;
#pragma unroll
    for (int m = 0; m < 4; m++) {
#pragma unroll
        for (int n = 0; n < 4; n++) {
            int c = cbase + n * 16;
            float bb = bias[c];
#pragma unroll
            for (int j = 0; j < 4; j++) {
                int r = rbase + m * 16 + j;
                int orow = (r & 15) * SEQ + (r >> 4);   // [B,S,V] layout
                C[(size_t)orow * N + c] = acc[m][n][j] + bb;
            }
        }
    }
}

// ---------------- fused balanced 2-layer persistent LSTM ----------------------
// 256 blocks x 256 threads. EVERY block owns 4 L0 units AND 4 L1 units.
// Step s: L0 computes t=s, L1 computes t=s-1; both consume seq0 slot s.
// seq slots are write-once-then-read: publishes go via agent atomics (L3
// write-through) + vmcnt-ordered arrive; READS are normal cached loads (L2-
// shared within an XCD; safe because each address's first access this dispatch
// is the post-barrier read, and dispatch-boundary acquire invalidates L2).
__global__ __launch_bounds__(256, 1) void lstm_fused(
    const float* __restrict__ Whh0, const float* __restrict__ Whh1,
    const float* __restrict__ G0,        // [4096][4096] rows t*16+b (L0 x-proj + biases)
    const u16* __restrict__ wih_hi,      // pre-swizzled [256][2048] x 16B
    const u16* __restrict__ wih_lo,
    const float* __restrict__ bi1, const float* __restrict__ bh1,
    const float* __restrict__ c0in,      // [2][16][1024]
    float* __restrict__ c_tail, float* __restrict__ h_tail,  // [2][16][1024]
    u16* __restrict__ seq0, u16* __restrict__ seq1,          // [NSLOT hi | NSLOT lo]
    u32* __restrict__ arrive) {
    __shared__ __align__(16) char lds[139264];
    char* W0hi = lds;                   // [16 rows][2048B] swizzled Whh0 hi
    char* W0lo = lds + 32768;
    char* W1hi = lds + 65536;
    char* W1lo = lds + 98304;
    float* Pw = (float*)(lds + 131072); // [2 layer][4 wave][64 lane][4] = 8 KB

    const int tid = threadIdx.x;
    const int bid = blockIdx.x;
    const int j0 = bid * 4;                  // 4 units per layer per block
    const int w = tid >> 6, l = tid & 63;
    const int lb = l & 15, hi4 = l >> 4, xr = l & 7;

    // ---- one-time: stage Whh0/Whh1 slices (16 gate-cols x 1024) hi/lo ----
#pragma unroll
    for (int lay = 0; lay < 2; lay++) {
        const float* Whh = lay ? Whh1 : Whh0;
        char* dH = lay ? W1hi : W0hi;
        char* dL = lay ? W1lo : W0lo;
        for (int i = 0; i < 8; i++) {
            int q = i * 256 + tid;            // 16B chunk id 0..2047
            int row = q >> 7, cin = q & 127;  // row = gate-col (0..15)
            int nrow = (row >> 2) * HIDDEN + j0 + (row & 3);
            const float* src = Whh + (size_t)nrow * HIDDEN + cin * 8;
            int dst = row * 2048 + ((cin ^ (row & 7)) << 4);
            u32 hw[4], lw[4];
#pragma unroll
            for (int e = 0; e < 4; e++) {
                float x0 = src[2 * e], x1 = src[2 * e + 1];
                u32 hb0 = f2bf(x0), hb1 = f2bf(x1);
                hw[e] = hb0 | (hb1 << 16);
                lw[e] = f2bf(x0 - bf2f(hb0)) | (f2bf(x1 - bf2f(hb1)) << 16);
            }
            *(uint4*)(dH + dst) = make_uint4(hw[0], hw[1], hw[2], hw[3]);
            *(uint4*)(dL + dst) = make_uint4(lw[0], lw[1], lw[2], lw[3]);
        }
    }

    // pointwise state (wave 0): lane l -> batch lb, unit jj = hi4 (one per layer)
    float c0r = 0.f, c1r = 0.f;
    float g00 = 0, g01 = 0, g02 = 0, g03 = 0;   // L0 gates (prefetched from G0)
    float g10 = 0, g11 = 0, g12 = 0, g13 = 0;   // L1 gates (constant biases)
    if (tid < 64) {
        c0r = c0in[lb * HIDDEN + j0 + hi4];
        c1r = c0in[16384 + lb * HIDDEN + j0 + hi4];
        const float* gp = G0 + (size_t)lb * GATES + j0 + hi4;   // t = 0
        g00 = gp[0]; g01 = gp[HIDDEN]; g02 = gp[2 * HIDDEN]; g03 = gp[3 * HIDDEN];
        g10 = bi1[j0 + hi4] + bh1[j0 + hi4];
        g11 = bi1[HIDDEN + j0 + hi4] + bh1[HIDDEN + j0 + hi4];
        g12 = bi1[2 * HIDDEN + j0 + hi4] + bh1[2 * HIDDEN + j0 + hi4];
        g13 = bi1[3 * HIDDEN + j0 + hi4] + bh1[3 * HIDDEN + j0 + hi4];
    }
    __syncthreads();

    const u64* s0h = (const u64*)seq0;
    const u64* s0l = (const u64*)(seq0 + SEQ_LOU16);
    const u64* s1h = (const u64*)seq1;
    const u64* s1l = (const u64*)(seq1 + SEQ_LOU16);
    const int fb = lb * 256 + hi4 * 2;            // u64 base within a slot
    const size_t wbase = (size_t)bid * 2048 + l;  // wih fragment entry base

    union u4bf { uint4 u; bf16x8 v; };

    for (int s = 0; s <= SEQ; s++) {
        const bool actL0 = (s < SEQ);
        const bool actL1 = (s >= 1);

        // ---- up-front normal loads (one clause; L2-shared within XCD) ----
        u4bf xh8[8], xl8[8], yh8[8], yl8[8];
        {
            const int base = s * 4096 + fb;
#pragma unroll
            for (int ss = 0; ss < 8; ss++) {
                const int idx = base + (w * 8 + ss) * 8;
                xh8[ss].u = *(const uint4*)(s0h + idx);
                xl8[ss].u = *(const uint4*)(s0l + idx);
            }
        }
        if (actL1) {
            const int base = (s - 1) * 4096 + fb;
#pragma unroll
            for (int ss = 0; ss < 8; ss++) {
                const int idx = base + (w * 8 + ss) * 8;
                yh8[ss].u = *(const uint4*)(s1h + idx);
                yl8[ss].u = *(const uint4*)(s1l + idx);
            }
        }

        if (actL0) {
            f32x4 a0 = {0.f,0.f,0.f,0.f}, a1 = {0.f,0.f,0.f,0.f}, a2 = {0.f,0.f,0.f,0.f};
#pragma unroll
            for (int ss = 0; ss < 8; ss++) {
                const int s32 = w * 8 + ss;
                const int off = lb * 2048 + (((s32 * 4 + hi4) ^ xr) << 4);
                bf16x8 ah = *(const bf16x8*)(W0hi + off);
                bf16x8 al = *(const bf16x8*)(W0lo + off);
                a0 = __builtin_amdgcn_mfma_f32_16x16x32_bf16(ah, xh8[ss].v, a0, 0, 0, 0);
                a1 = __builtin_amdgcn_mfma_f32_16x16x32_bf16(al, xh8[ss].v, a1, 0, 0, 0);
                a2 = __builtin_amdgcn_mfma_f32_16x16x32_bf16(ah, xl8[ss].v, a2, 0, 0, 0);
            }
            f32x4 v0 = a0 + a1 + a2;
            *(f32x4*)&Pw[((0 * 4 + w) * 64 + l) * 4] = v0;
        }

        if (actL1) {
            f32x4 a0 = {0.f,0.f,0.f,0.f}, a1 = {0.f,0.f,0.f,0.f}, a2 = {0.f,0.f,0.f,0.f};
            // input projection: A = pre-swizzled wih frags (L2-resident stream)
#pragma unroll
            for (int ss = 0; ss < 8; ss++) {
                const size_t e = wbase + (size_t)(w * 8 + ss) * 64;
                bf16x8 ah = *(const bf16x8*)(wih_hi + e * 8);
                bf16x8 al = *(const bf16x8*)(wih_lo + e * 8);
                a0 = __builtin_amdgcn_mfma_f32_16x16x32_bf16(ah, xh8[ss].v, a0, 0, 0, 0);
                a1 = __builtin_amdgcn_mfma_f32_16x16x32_bf16(al, xh8[ss].v, a1, 0, 0, 0);
                a2 = __builtin_amdgcn_mfma_f32_16x16x32_bf16(ah, xl8[ss].v, a2, 0, 0, 0);
            }
            // recurrent: A = LDS Whh1
#pragma unroll
            for (int ss = 0; ss < 8; ss++) {
                const int s32 = w * 8 + ss;
                const int off = lb * 2048 + (((s32 * 4 + hi4) ^ xr) << 4);
                bf16x8 ah = *(const bf16x8*)(W1hi + off);
                bf16x8 al = *(const bf16x8*)(W1lo + off);
                a0 = __builtin_amdgcn_mfma_f32_16x16x32_bf16(ah, yh8[ss].v, a0, 0, 0, 0);
                a1 = __builtin_amdgcn_mfma_f32_16x16x32_bf16(al, yh8[ss].v, a1, 0, 0, 0);
                a2 = __builtin_amdgcn_mfma_f32_16x16x32_bf16(ah, yl8[ss].v, a2, 0, 0, 0);
            }
            f32x4 v1 = a0 + a1 + a2;
            *(f32x4*)&Pw[((1 * 4 + w) * 64 + l) * 4] = v1;
        }
        __syncthreads();

        if (tid < 64) {
            // D layout: Pw[(lay*4+w)*64 + ll][jw] = D[c=(ll>>4)*4+jw][b=ll&15].
            if (actL0) {
                float pre[4];
#pragma unroll
                for (int g = 0; g < 4; g++) {
                    const int ll = (g << 4) | lb;
                    pre[g] = Pw[((0 * 4 + 0) * 64 + ll) * 4 + hi4]
                           + Pw[((0 * 4 + 1) * 64 + ll) * 4 + hi4]
                           + Pw[((0 * 4 + 2) * 64 + ll) * 4 + hi4]
                           + Pw[((0 * 4 + 3) * 64 + ll) * 4 + hi4];
                }
                const float ig = 1.f / (1.f + __expf(-(pre[0] + g00)));
                const float fg = 1.f / (1.f + __expf(-(pre[1] + g01)));
                const float gt = tanhf(pre[2] + g02);
                const float og = 1.f / (1.f + __expf(-(pre[3] + g03)));
                c0r = fg * c0r + ig * gt;
                const float hv = og * tanhf(c0r);
                if (s == SEQ - 1) {
                    h_tail[lb * HIDDEN + j0 + hi4] = hv;
                    c_tail[lb * HIDDEN + j0 + hi4] = c0r;
                }
                float q0 = __shfl(hv, 0 + l), q1 = __shfl(hv, 16 + l);
                float q2 = __shfl(hv, 32 + l), q3 = __shfl(hv, 48 + l);
                if (l < 16) {
                    u32 hb0 = f2bf(q0), hb1 = f2bf(q1), hb2 = f2bf(q2), hb3 = f2bf(q3);
                    u64 hq = (u64)(hb0 | (hb1 << 16)) | ((u64)(hb2 | (hb3 << 16)) << 32);
                    u32 lb0 = f2bf(q0 - bf2f(hb0)), lb1 = f2bf(q1 - bf2f(hb1));
                    u32 lb2 = f2bf(q2 - bf2f(hb2)), lb3 = f2bf(q3 - bf2f(hb3));
                    u64 lq = (u64)(lb0 | (lb1 << 16)) | ((u64)(lb2 | (lb3 << 16)) << 32);
                    const int iq = (s + 1) * 4096 + l * 256 + bid;
                    astore((u64*)seq0 + iq, hq);
                    astore((u64*)(seq0 + SEQ_LOU16) + iq, lq);
                }
            }
            if (actL1) {
                float pre[4];
#pragma unroll
                for (int g = 0; g < 4; g++) {
                    const int ll = (g << 4) | lb;
                    pre[g] = Pw[((1 * 4 + 0) * 64 + ll) * 4 + hi4]
                           + Pw[((1 * 4 + 1) * 64 + ll) * 4 + hi4]
                           + Pw[((1 * 4 + 2) * 64 + ll) * 4 + hi4]
                           + Pw[((1 * 4 + 3) * 64 + ll) * 4 + hi4];
                }
                const float ig = 1.f / (1.f + __expf(-(pre[0] + g10)));
                const float fg = 1.f / (1.f + __expf(-(pre[1] + g11)));
                const float gt = tanhf(pre[2] + g12);
                const float og = 1.f / (1.f + __expf(-(pre[3] + g13)));
                c1r = fg * c1r + ig * gt;
                const float hv = og * tanhf(c1r);
                if (s == SEQ) {
                    h_tail[16384 + lb * HIDDEN + j0 + hi4] = hv;
                    c_tail[16384 + lb * HIDDEN + j0 + hi4] = c1r;
                }
                float q0 = __shfl(hv, 0 + l), q1 = __shfl(hv, 16 + l);
                float q2 = __shfl(hv, 32 + l), q3 = __shfl(hv, 48 + l);
                if (l < 16) {
                    u32 hb0 = f2bf(q0), hb1 = f2bf(q1), hb2 = f2bf(q2), hb3 = f2bf(q3);
                    u64 hq = (u64)(hb0 | (hb1 << 16)) | ((u64)(hb2 | (hb3 << 16)) << 32);
                    u32 lb0 = f2bf(q0 - bf2f(hb0)), lb1 = f2bf(q1 - bf2f(hb1));
                    u32 lb2 = f2bf(q2 - bf2f(hb2)), lb3 = f2bf(q3 - bf2f(hb3));
                    u64 lq = (u64)(lb0 | (lb1 << 16)) | ((u64)(lb2 | (lb3 << 16)) << 32);
                    const int iq = s * 4096 + l * 256 + bid;
                    astore((u64*)seq1 + iq, hq);
                    astore((u64*)(seq1 + SEQ_LOU16) + iq, lq);
                }
            }
        }

        if (s < SEQ) {
            if (tid < 64) {
                asm volatile("s_waitcnt vmcnt(0)" ::: "memory");  // drain publishes
                if (tid == 0)
                    __hip_atomic_store(&arrive[bid], (u32)(s + 1), __ATOMIC_RELAXED,
                                       __HIP_MEMORY_SCOPE_AGENT);
                // off critical path: prefetch next step's G0 gates
                if (s + 1 < SEQ) {
                    const float* gp = G0 + (size_t)((s + 1) * BATCH + lb) * GATES + j0 + hi4;
                    g00 = gp[0]; g01 = gp[HIDDEN];
                    g02 = gp[2 * HIDDEN]; g03 = gp[3 * HIDDEN];
                }
                const u32 epoch = (u32)(s + 1);
                const int i0 = l * 4;
                for (;;) {
                    u32 q0 = __hip_atomic_load(&arrive[i0 + 0], __ATOMIC_RELAXED,
                                               __HIP_MEMORY_SCOPE_AGENT);
                    u32 q1 = __hip_atomic_load(&arrive[i0 + 1], __ATOMIC_RELAXED,
                                               __HIP_MEMORY_SCOPE_AGENT);
                    u32 q2 = __hip_atomic_load(&arrive[i0 + 2], __ATOMIC_RELAXED,
                                               __HIP_MEMORY_SCOPE_AGENT);
                    u32 q3 = __hip_atomic_load(&arrive[i0 + 3], __ATOMIC_RELAXED,
                                               __HIP_MEMORY_SCOPE_AGENT);
                    u32 m01 = q0 < q1 ? q0 : q1;
                    u32 m23 = q2 < q3 ? q2 : q3;
                    u32 mn = m01 < m23 ? m01 : m23;
                    if (__all(mn >= epoch)) break;
                    __builtin_amdgcn_s_sleep(2);
                }
                asm volatile("" ::: "memory");   // compiler barrier only
            }
            __syncthreads();
        }
    }
}

// ---------------- init & tails ----------------
__global__ void init_state(const float* __restrict__ h0, u16* __restrict__ seq0,
                           u16* __restrict__ seq1, u32* __restrict__ arrive) {
    int gid = blockIdx.x * 256 + threadIdx.x;  // 32768 = 2*16*1024
    if (gid < 256) arrive[gid] = 0;
    int layer = gid >> 14, b = (gid >> 10) & 15, j = gid & 1023;
    float h = h0[gid];
    u32 hb = f2bf(h);
    u32 lbits = f2bf(h - bf2f(hb));
    u16* sq = layer ? seq1 : seq0;
    sq[b * 1024 + j] = (u16)hb;                 // slot 0 hi
    sq[SEQ_LOU16 + b * 1024 + j] = (u16)lbits;  // slot 0 lo
}

__global__ void write_tails(const float* __restrict__ h_tail, const float* __restrict__ c_tail,
                            float* __restrict__ out) {
    int gid = blockIdx.x * 256 + threadIdx.x;  // 32768
    out[LOGITS_SZ + gid] = h_tail[gid];
    out[LOGITS_SZ + 32768 + gid] = c_tail[gid];
}

// ---------------- launch ----------------
extern "C" void kernel_launch(void* const* d_in, const int* in_sizes, int n_in,
                              void* d_out, int out_size, void* d_ws, size_t ws_size,
                              hipStream_t stream) {
    const int* x = (const int*)d_in[0];
    const float* h0 = (const float*)d_in[1];
    const float* c0 = (const float*)d_in[2];
    const float* emb = (const float*)d_in[3];
    const float* W_ih0 = (const float*)d_in[4];
    const float* W_hh0 = (const float*)d_in[5];
    const float* b_ih0 = (const float*)d_in[6];
    const float* b_hh0 = (const float*)d_in[7];
    const float* W_ih1 = (const float*)d_in[8];
    const float* W_hh1 = (const float*)d_in[9];
    const float* b_ih1 = (const float*)d_in[10];
    const float* b_hh1 = (const float*)d_in[11];
    const float* fc_W = (const float*)d_in[12];
    const float* fc_b = (const float*)d_in[13];
    float* out = (float*)d_out;
    float* ws = (float*)d_ws;

    // workspace layout (float offsets)
    const size_t OFF_G = 0;                                   // G0; later fc_W bf16
    const size_t OFF_X0 = OFF_G + (size_t)MROWS * GATES;
    const size_t OFF_SEQ0 = OFF_X0 + (size_t)MROWS * EMBED;
    const size_t SEQ_FLOATS = (size_t)2 * NSLOT * SEQ_SLOTU16 / 2;
    const size_t OFF_SEQ1 = OFF_SEQ0 + SEQ_FLOATS;
    const size_t OFF_WIHH = OFF_SEQ1 + SEQ_FLOATS;
    const size_t OFF_WIHL = OFF_WIHH + (size_t)GATES * HIDDEN / 2;
    const size_t OFF_HT = OFF_WIHL + (size_t)GATES * HIDDEN / 2;
    const size_t OFF_CT = OFF_HT + 2 * BATCH * HIDDEN;
    const size_t OFF_AR = OFF_CT + 2 * BATCH * HIDDEN;

    u16* seq0 = (u16*)(ws + OFF_SEQ0);
    u16* seq1 = (u16*)(ws + OFF_SEQ1);
    u16* wihH = (u16*)(ws + OFF_WIHH);
    u16* wihL = (u16*)(ws + OFF_WIHL);
    u32* arrive = (u32*)(ws + OFF_AR);

    init_state<<<128, 256, 0, stream>>>(h0, seq0, seq1, arrive);
    embed_kernel<<<MROWS, 128, 0, stream>>>(x, emb, ws + OFF_X0);
    wih_swizzle_kernel<<<256, 256, 0, stream>>>(W_ih1, wihH, wihL);

    // layer-0 input projection for all timesteps (includes both layer-0 biases)
    gemm_bt<<<dim3(GATES / 128, MROWS / 128), 256, 0, stream>>>(
        ws + OFF_X0, W_ih0, b_ih0, b_hh0, ws + OFF_G, MROWS, GATES, EMBED, 0);

    // fused balanced pipelined recurrence (both layers)
    {
        const float* Whh0p = W_hh0;
        const float* Whh1p = W_hh1;
        const float* Gp = ws + OFF_G;
        const u16* wh = wihH;
        const u16* wl = wihL;
        const float* bi = b_ih1;
        const float* bh = b_hh1;
        const float* ci = c0;
        float* ct = ws + OFF_CT;
        float* ht = ws + OFF_HT;
        u16* s0 = seq0;
        u16* s1 = seq1;
        u32* ar = arrive;
        void* args[] = {(void*)&Whh0p, (void*)&Whh1p, (void*)&Gp, (void*)&wh,
                        (void*)&wl, (void*)&bi, (void*)&bh, (void*)&ci,
                        (void*)&ct, (void*)&ht, (void*)&s0, (void*)&s1, (void*)&ar};
        hipLaunchCooperativeKernel((void*)lstm_fused, dim3(256), dim3(256), args, 0, stream);
    }

    // FC via bf16 MFMA: A = seq1 hi slots 1..256 directly; B = fc_W bf16 (G0 dead)
    f32_to_bf16_kernel<<<4096, 256, 0, stream>>>(fc_W, (u16*)(ws + OFF_G), VOCAB * HIDDEN / 8);
    fc_mfma<<<dim3(VOCAB / 128, MROWS / 128), 256, 0, stream>>>(
        seq1 + SEQ_SLOTU16, (const u16*)(ws + OFF_G), fc_b, out);

    write_tails<<<128, 256, 0, stream>>>(ws + OFF_HT, ws + OFF_CT, out);
}

// Round 11
// 3864.717 us; speedup vs baseline: 1.5360x; 1.0389x over previous
//
#include <hip/hip_runtime.h>
#include <hip/hip_bf16.h>
#include <cmath>

// Problem constants
#define BATCH 16
#define SEQ 256
#define EMBED 512
#define HIDDEN 1024
#define GATES 4096       // 4*HIDDEN
#define VOCAB 32000
#define MROWS 4096       // BATCH*SEQ
#define LOGITS_SZ 131072000  // 16*256*32000

#define NSLOT 257                    // h-history slots (init + 256 steps)
#define SEQ_SLOTU16 16384            // u16 per slot: 16 batch x 1024
#define SEQ_LOU16 (NSLOT * SEQ_SLOTU16)

typedef unsigned int u32;
typedef unsigned short u16;
typedef unsigned long long u64;
typedef __attribute__((ext_vector_type(8))) short bf16x8;
typedef __attribute__((ext_vector_type(4))) float f32x4;

#define AS1 __attribute__((address_space(1)))
#define AS3 __attribute__((address_space(3)))

// ---------------- helpers ----------------
__device__ __forceinline__ u32 f2bf(float f) {          // RNE fp32->bf16 (bits)
    u32 u = __float_as_uint(f);
    return (u + 0x7fffu + ((u >> 16) & 1u)) >> 16;
}
__device__ __forceinline__ float bf2f(u32 b) { return __uint_as_float(b << 16); }

__device__ __forceinline__ void astore(u64* p, u64 v) {
    __hip_atomic_store(p, v, __ATOMIC_RELAXED, __HIP_MEMORY_SCOPE_AGENT);
}

// ---------------- embedding gather -> bf16 hi/lo planes ----------------
__global__ void embed_hl_kernel(const int* __restrict__ x, const float* __restrict__ emb,
                                u16* __restrict__ XH, u16* __restrict__ XL) {
    int r = blockIdx.x;            // r = s*16 + b
    int s = r >> 4, b = r & 15;
    int tok = x[b * SEQ + s];
    const float4* src = (const float4*)(emb + (size_t)tok * EMBED);
    int i = threadIdx.x;           // 0..127, 4 elems each
    float4 a = src[i];
    u32 h0 = f2bf(a.x), h1 = f2bf(a.y), h2 = f2bf(a.z), h3 = f2bf(a.w);
    u64 hq = (u64)(h0 | (h1 << 16)) | ((u64)(h2 | (h3 << 16)) << 32);
    u32 l0 = f2bf(a.x - bf2f(h0)), l1 = f2bf(a.y - bf2f(h1));
    u32 l2 = f2bf(a.z - bf2f(h2)), l3 = f2bf(a.w - bf2f(h3));
    u64 lq = (u64)(l0 | (l1 << 16)) | ((u64)(l2 | (l3 << 16)) << 32);
    ((u64*)(XH + (size_t)r * EMBED))[i] = hq;
    ((u64*)(XL + (size_t)r * EMBED))[i] = lq;
}

// ---------------- fp32 -> bf16 conversion (hi only, for fc_W) ----------------
__global__ __launch_bounds__(256) void f32_to_bf16_kernel(
    const float* __restrict__ in, u16* __restrict__ out, int n8) {
    for (int i = blockIdx.x * 256 + threadIdx.x; i < n8; i += gridDim.x * 256) {
        float4 a = ((const float4*)in)[2 * (size_t)i + 0];
        float4 b = ((const float4*)in)[2 * (size_t)i + 1];
        uint4 o;
        o.x = f2bf(a.x) | (f2bf(a.y) << 16);
        o.y = f2bf(a.z) | (f2bf(a.w) << 16);
        o.z = f2bf(b.x) | (f2bf(b.y) << 16);
        o.w = f2bf(b.z) | (f2bf(b.w) << 16);
        ((uint4*)out)[i] = o;
    }
}

// ---------------- fp32 -> bf16 hi+lo split ----------------
__global__ __launch_bounds__(256) void f32_to_bf16hl_kernel(
    const float* __restrict__ in, u16* __restrict__ hi, u16* __restrict__ lo, int n4) {
    for (int i = blockIdx.x * 256 + threadIdx.x; i < n4; i += gridDim.x * 256) {
        float4 a = ((const float4*)in)[i];
        u32 h0 = f2bf(a.x), h1 = f2bf(a.y), h2 = f2bf(a.z), h3 = f2bf(a.w);
        u64 hq = (u64)(h0 | (h1 << 16)) | ((u64)(h2 | (h3 << 16)) << 32);
        u32 l0 = f2bf(a.x - bf2f(h0)), l1 = f2bf(a.y - bf2f(h1));
        u32 l2 = f2bf(a.z - bf2f(h2)), l3 = f2bf(a.w - bf2f(h3));
        u64 lq = (u64)(l0 | (l1 << 16)) | ((u64)(l2 | (l3 << 16)) << 32);
        ((u64*)hi)[i] = hq;
        ((u64*)lo)[i] = lq;
    }
}

// ---------------- W_ih1 pre-swizzle into MFMA fragment order ----------------
__global__ __launch_bounds__(256) void wih_swizzle_kernel(
    const float* __restrict__ W, u16* __restrict__ hi, u16* __restrict__ lo) {
    int bid = blockIdx.x, tid = threadIdx.x;
    int j0 = bid * 4;
#pragma unroll
    for (int i = 0; i < 8; i++) {
        int q = i * 256 + tid;           // 0..2047
        int s32 = q >> 6, l = q & 63;
        int row = l & 15, hi4 = l >> 4;
        int nrow = (row >> 2) * HIDDEN + j0 + (row & 3);
        int k = s32 * 32 + hi4 * 8;
        const float* src = W + (size_t)nrow * HIDDEN + k;
        u32 hw[4], lw[4];
#pragma unroll
        for (int e = 0; e < 4; e++) {
            float x0 = src[2 * e], x1 = src[2 * e + 1];
            u32 h0 = f2bf(x0), h1 = f2bf(x1);
            hw[e] = h0 | (h1 << 16);
            lw[e] = f2bf(x0 - bf2f(h0)) | (f2bf(x1 - bf2f(h1)) << 16);
        }
        size_t e0 = (size_t)bid * 2048 + q;
        ((uint4*)hi)[e0] = make_uint4(hw[0], hw[1], hw[2], hw[3]);
        ((uint4*)lo)[e0] = make_uint4(lw[0], lw[1], lw[2], lw[3]);
    }
}

// ---------------- split-precision MFMA input projection (layer 0) ----------
// G0[r][n] = sum_k X[r][k]*Wih0[n][k] + b1[n] + b2[n], via hi/lo 3-chain MFMA.
__global__ __launch_bounds__(256) void xproj_mfma(
    const u16* __restrict__ Ahi, const u16* __restrict__ Alo,   // [MROWS][512]
    const u16* __restrict__ Bhi, const u16* __restrict__ Blo,   // [4096][512]
    const float* __restrict__ b1, const float* __restrict__ b2,
    float* __restrict__ C) {                                    // [MROWS][4096]
    const int K = EMBED;           // 512
    const int N = GATES;
    __shared__ char smem[32768];
    char* AsH = smem;
    char* AsL = smem + 8192;
    char* BsH = smem + 16384;
    char* BsL = smem + 24576;

    int tid = threadIdx.x;
    int w = tid >> 6, l = tid & 63;
    int bn = blockIdx.x, bm = blockIdx.y;
    int wr = w >> 1, wc = w & 1;
    int lr = l & 15, lk = l >> 4;

    f32x4 acc[4][4];
#pragma unroll
    for (int m = 0; m < 4; m++)
#pragma unroll
        for (int n = 0; n < 4; n++) acc[m][n] = {0.f, 0.f, 0.f, 0.f};

    int srow = tid >> 2, skc = (tid & 3) * 8;
    const u16* gah0 = Ahi + (size_t)(bm * 128 + srow) * K + skc;
    const u16* gah1 = Ahi + (size_t)(bm * 128 + 64 + srow) * K + skc;
    const u16* gal0 = Alo + (size_t)(bm * 128 + srow) * K + skc;
    const u16* gal1 = Alo + (size_t)(bm * 128 + 64 + srow) * K + skc;
    const u16* gbh0 = Bhi + (size_t)(bn * 128 + srow) * K + skc;
    const u16* gbh1 = Bhi + (size_t)(bn * 128 + 64 + srow) * K + skc;
    const u16* gbl0 = Blo + (size_t)(bn * 128 + srow) * K + skc;
    const u16* gbl1 = Blo + (size_t)(bn * 128 + 64 + srow) * K + skc;
    char* lah0 = AsH + w * 1024;       char* lah1 = AsH + 4096 + w * 1024;
    char* lal0 = AsL + w * 1024;       char* lal1 = AsL + 4096 + w * 1024;
    char* lbh0 = BsH + w * 1024;       char* lbh1 = BsH + 4096 + w * 1024;
    char* lbl0 = BsL + w * 1024;       char* lbl1 = BsL + 4096 + w * 1024;

    int afo[4], bfo[4];
#pragma unroll
    for (int m = 0; m < 4; m++) afo[m] = (wr * 64 + m * 16 + lr) * 64 + lk * 16;
#pragma unroll
    for (int n = 0; n < 4; n++) bfo[n] = (wc * 64 + n * 16 + lr) * 64 + lk * 16;

    for (int k0 = 0; k0 < K; k0 += 32) {
        __syncthreads();
        __builtin_amdgcn_global_load_lds((const AS1 u32*)(const void*)(gah0 + k0),
                                         (AS3 u32*)(void*)lah0, 16, 0, 0);
        __builtin_amdgcn_global_load_lds((const AS1 u32*)(const void*)(gah1 + k0),
                                         (AS3 u32*)(void*)lah1, 16, 0, 0);
        __builtin_amdgcn_global_load_lds((const AS1 u32*)(const void*)(gal0 + k0),
                                         (AS3 u32*)(void*)lal0, 16, 0, 0);
        __builtin_amdgcn_global_load_lds((const AS1 u32*)(const void*)(gal1 + k0),
                                         (AS3 u32*)(void*)lal1, 16, 0, 0);
        __builtin_amdgcn_global_load_lds((const AS1 u32*)(const void*)(gbh0 + k0),
                                         (AS3 u32*)(void*)lbh0, 16, 0, 0);
        __builtin_amdgcn_global_load_lds((const AS1 u32*)(const void*)(gbh1 + k0),
                                         (AS3 u32*)(void*)lbh1, 16, 0, 0);
        __builtin_amdgcn_global_load_lds((const AS1 u32*)(const void*)(gbl0 + k0),
                                         (AS3 u32*)(void*)lbl0, 16, 0, 0);
        __builtin_amdgcn_global_load_lds((const AS1 u32*)(const void*)(gbl1 + k0),
                                         (AS3 u32*)(void*)lbl1, 16, 0, 0);
        __syncthreads();

        bf16x8 ah[4], al[4], bh[4], bl[4];
#pragma unroll
        for (int m = 0; m < 4; m++) {
            ah[m] = *(const bf16x8*)(AsH + afo[m]);
            al[m] = *(const bf16x8*)(AsL + afo[m]);
        }
#pragma unroll
        for (int n = 0; n < 4; n++) {
            bh[n] = *(const bf16x8*)(BsH + bfo[n]);
            bl[n] = *(const bf16x8*)(BsL + bfo[n]);
        }
#pragma unroll
        for (int m = 0; m < 4; m++)
#pragma unroll
            for (int n = 0; n < 4; n++) {
                acc[m][n] = __builtin_amdgcn_mfma_f32_16x16x32_bf16(ah[m], bh[n], acc[m][n], 0, 0, 0);
                acc[m][n] = __builtin_amdgcn_mfma_f32_16x16x32_bf16(al[m], bh[n], acc[m][n], 0, 0, 0);
                acc[m][n] = __builtin_amdgcn_mfma_f32_16x16x32_bf16(ah[m], bl[n], acc[m][n], 0, 0, 0);
            }
    }

    int rbase = bm * 128 + wr * 64 + lk * 4;
    int cbase = bn * 128 + wc * 64 + lr;
#pragma unroll
    for (int m = 0; m < 4; m++) {
#pragma unroll
        for (int n = 0; n < 4; n++) {
            int c = cbase + n * 16;
            float bb = b1[c] + b2[c];
#pragma unroll
            for (int j = 0; j < 4; j++) {
                int r = rbase + m * 16 + j;
                C[(size_t)r * N + c] = acc[m][n][j] + bb;
            }
        }
    }
}

// ---------------- bf16 MFMA FC GEMM ----------------
__global__ __launch_bounds__(256) void fc_mfma(
    const u16* __restrict__ Abf,   // [MROWS][1024] bf16
    const u16* __restrict__ Bbf,   // [VOCAB][1024] bf16
    const float* __restrict__ bias,
    float* __restrict__ C) {
    const int K = HIDDEN;
    const int N = VOCAB;
    __shared__ char smem[16384];
    char* As = smem;
    char* Bs = smem + 8192;

    int tid = threadIdx.x;
    int w = tid >> 6, l = tid & 63;
    int bn = blockIdx.x, bm = blockIdx.y;
    int wr = w >> 1, wc = w & 1;
    int lr = l & 15, lk = l >> 4;

    f32x4 acc[4][4];
#pragma unroll
    for (int m = 0; m < 4; m++)
#pragma unroll
        for (int n = 0; n < 4; n++) acc[m][n] = {0.f, 0.f, 0.f, 0.f};

    int srow = tid >> 2, skc = (tid & 3) * 8;
    const u16* ga0 = Abf + (size_t)(bm * 128 + srow) * K + skc;
    const u16* ga1 = Abf + (size_t)(bm * 128 + 64 + srow) * K + skc;
    const u16* gb0 = Bbf + (size_t)(bn * 128 + srow) * K + skc;
    const u16* gb1 = Bbf + (size_t)(bn * 128 + 64 + srow) * K + skc;
    char* la0 = As + w * 1024;
    char* la1 = As + 4096 + w * 1024;
    char* lb0 = Bs + w * 1024;
    char* lb1 = Bs + 4096 + w * 1024;

    int afo[4], bfo[4];
#pragma unroll
    for (int m = 0; m < 4; m++) afo[m] = (wr * 64 + m * 16 + lr) * 64 + lk * 16;
#pragma unroll
    for (int n = 0; n < 4; n++) bfo[n] = (wc * 64 + n * 16 + lr) * 64 + lk * 16;

    for (int k0 = 0; k0 < K; k0 += 32) {
        __syncthreads();
        __builtin_amdgcn_global_load_lds((const AS1 u32*)(const void*)(ga0 + k0),
                                         (AS3 u32*)(void*)la0, 16, 0, 0);
        __builtin_amdgcn_global_load_lds((const AS1 u32*)(const void*)(ga1 + k0),
                                         (AS3 u32*)(void*)la1, 16, 0, 0);
        __builtin_amdgcn_global_load_lds((const AS1 u32*)(const void*)(gb0 + k0),
                                         (AS3 u32*)(void*)lb0, 16, 0, 0);
        __builtin_amdgcn_global_load_lds((const AS1 u32*)(const void*)(gb1 + k0),
                                         (AS3 u32*)(void*)lb1, 16, 0, 0);
        __syncthreads();

        bf16x8 af[4], bfr[4];
#pragma unroll
        for (int m = 0; m < 4; m++) af[m] = *(const bf16x8*)(As + afo[m]);
#pragma unroll
        for (int n = 0; n < 4; n++) bfr[n] = *(const bf16x8*)(Bs + bfo[n]);
#pragma unroll
        for (int m = 0; m < 4; m++)
#pragma unroll
            for (int n = 0; n < 4; n++)
                acc[m][n] = __builtin_amdgcn_mfma_f32_16x16x32_bf16(
                    af[m], bfr[n], acc[m][n], 0, 0, 0);
    }

    int rbase = bm * 128 + wr * 64 + lk * 4;
    int cbase = bn * 128 + wc * 64 + lr;
#pragma unroll
    for (int m = 0; m < 4; m++) {
#pragma unroll
        for (int n = 0; n < 4; n++) {
            int c = cbase + n * 16;
            float bb = bias[c];
#pragma unroll
            for (int j = 0; j < 4; j++) {
                int r = rbase + m * 16 + j;
                int orow = (r & 15) * SEQ + (r >> 4);   // [B,S,V] layout
                C[(size_t)orow * N + c] = acc[m][n][j] + bb;
            }
        }
    }
}

// ---------------- fused balanced 2-layer persistent LSTM (R9-proven) ---------
// 256 blocks x 256 threads. EVERY block owns 4 L0 units AND 4 L1 units.
// Step s: L0 computes t=s, L1 computes t=s-1; both consume seq0 slot s.
// Whh0/Whh1 hi/lo in LDS; W_ih1 streamed from L2 in pre-swizzled fragment
// order. Unified wave-0 pointwise tail + single-wave vmcnt->arrive->poll.
__global__ __launch_bounds__(256, 1) void lstm_fused(
    const float* __restrict__ Whh0, const float* __restrict__ Whh1,
    const float* __restrict__ G0,        // [4096][4096] rows t*16+b (L0 x-proj + biases)
    const u16* __restrict__ wih_hi,      // pre-swizzled [256][2048] x 16B
    const u16* __restrict__ wih_lo,
    const float* __restrict__ bi1, const float* __restrict__ bh1,
    const float* __restrict__ c0in,      // [2][16][1024]
    float* __restrict__ c_tail, float* __restrict__ h_tail,  // [2][16][1024]
    u16* __restrict__ seq0, u16* __restrict__ seq1,          // [NSLOT hi | NSLOT lo]
    u32* __restrict__ arrive) {
    __shared__ __align__(16) char lds[139264];
    char* W0hi = lds;                   // [16 rows][2048B] swizzled Whh0 hi
    char* W0lo = lds + 32768;
    char* W1hi = lds + 65536;
    char* W1lo = lds + 98304;
    float* Pw = (float*)(lds + 131072); // [2 layer][4 wave][64 lane][4] = 8 KB

    const int tid = threadIdx.x;
    const int bid = blockIdx.x;
    const int j0 = bid * 4;                  // 4 units per layer per block
    const int w = tid >> 6, l = tid & 63;
    const int lb = l & 15, hi4 = l >> 4, xr = l & 7;

    // ---- one-time: stage Whh0/Whh1 slices (16 gate-cols x 1024) hi/lo ----
#pragma unroll
    for (int lay = 0; lay < 2; lay++) {
        const float* Whh = lay ? Whh1 : Whh0;
        char* dH = lay ? W1hi : W0hi;
        char* dL = lay ? W1lo : W0lo;
        for (int i = 0; i < 8; i++) {
            int q = i * 256 + tid;            // 16B chunk id 0..2047
            int row = q >> 7, cin = q & 127;  // row = gate-col (0..15)
            int nrow = (row >> 2) * HIDDEN + j0 + (row & 3);
            const float* src = Whh + (size_t)nrow * HIDDEN + cin * 8;
            int dst = row * 2048 + ((cin ^ (row & 7)) << 4);
            u32 hw[4], lw[4];
#pragma unroll
            for (int e = 0; e < 4; e++) {
                float x0 = src[2 * e], x1 = src[2 * e + 1];
                u32 hb0 = f2bf(x0), hb1 = f2bf(x1);
                hw[e] = hb0 | (hb1 << 16);
                lw[e] = f2bf(x0 - bf2f(hb0)) | (f2bf(x1 - bf2f(hb1)) << 16);
            }
            *(uint4*)(dH + dst) = make_uint4(hw[0], hw[1], hw[2], hw[3]);
            *(uint4*)(dL + dst) = make_uint4(lw[0], lw[1], lw[2], lw[3]);
        }
    }

    // pointwise state (wave 0): lane l -> batch lb, unit jj = hi4 (one per layer)
    float c0r = 0.f, c1r = 0.f;
    float g00 = 0, g01 = 0, g02 = 0, g03 = 0;   // L0 gates (prefetched from G0)
    float g10 = 0, g11 = 0, g12 = 0, g13 = 0;   // L1 gates (constant biases)
    if (tid < 64) {
        c0r = c0in[lb * HIDDEN + j0 + hi4];
        c1r = c0in[16384 + lb * HIDDEN + j0 + hi4];
        const float* gp = G0 + (size_t)lb * GATES + j0 + hi4;   // t = 0
        g00 = gp[0]; g01 = gp[HIDDEN]; g02 = gp[2 * HIDDEN]; g03 = gp[3 * HIDDEN];
        g10 = bi1[j0 + hi4] + bh1[j0 + hi4];
        g11 = bi1[HIDDEN + j0 + hi4] + bh1[HIDDEN + j0 + hi4];
        g12 = bi1[2 * HIDDEN + j0 + hi4] + bh1[2 * HIDDEN + j0 + hi4];
        g13 = bi1[3 * HIDDEN + j0 + hi4] + bh1[3 * HIDDEN + j0 + hi4];
    }
    __syncthreads();

    const u64* s0h = (const u64*)seq0;
    const u64* s0l = (const u64*)(seq0 + SEQ_LOU16);
    const u64* s1h = (const u64*)seq1;
    const u64* s1l = (const u64*)(seq1 + SEQ_LOU16);
    const int fb = lb * 256 + hi4 * 2;            // u64 base within a slot
    const size_t wbase = (size_t)bid * 2048 + l;  // wih fragment entry base

    union u4bf { uint4 u; bf16x8 v; };

    for (int s = 0; s <= SEQ; s++) {
        const bool actL0 = (s < SEQ);
        const bool actL1 = (s >= 1);

        // ---- up-front loads (L2-shared within XCD) ----
        u4bf xh8[8], xl8[8], yh8[8], yl8[8];
        {
            const int base = s * 4096 + fb;
#pragma unroll
            for (int ss = 0; ss < 8; ss++) {
                const int idx = base + (w * 8 + ss) * 8;
                xh8[ss].u = *(const uint4*)(s0h + idx);
                xl8[ss].u = *(const uint4*)(s0l + idx);
            }
        }
        if (actL1) {
            const int base = (s - 1) * 4096 + fb;
#pragma unroll
            for (int ss = 0; ss < 8; ss++) {
                const int idx = base + (w * 8 + ss) * 8;
                yh8[ss].u = *(const uint4*)(s1h + idx);
                yl8[ss].u = *(const uint4*)(s1l + idx);
            }
        }

        if (actL0) {
            f32x4 a0 = {0.f,0.f,0.f,0.f}, a1 = {0.f,0.f,0.f,0.f}, a2 = {0.f,0.f,0.f,0.f};
#pragma unroll
            for (int ss = 0; ss < 8; ss++) {
                const int s32 = w * 8 + ss;
                const int off = lb * 2048 + (((s32 * 4 + hi4) ^ xr) << 4);
                bf16x8 ah = *(const bf16x8*)(W0hi + off);
                bf16x8 al = *(const bf16x8*)(W0lo + off);
                a0 = __builtin_amdgcn_mfma_f32_16x16x32_bf16(ah, xh8[ss].v, a0, 0, 0, 0);
                a1 = __builtin_amdgcn_mfma_f32_16x16x32_bf16(al, xh8[ss].v, a1, 0, 0, 0);
                a2 = __builtin_amdgcn_mfma_f32_16x16x32_bf16(ah, xl8[ss].v, a2, 0, 0, 0);
            }
            f32x4 v0 = a0 + a1 + a2;
            *(f32x4*)&Pw[((0 * 4 + w) * 64 + l) * 4] = v0;
        }

        if (actL1) {
            f32x4 a0 = {0.f,0.f,0.f,0.f}, a1 = {0.f,0.f,0.f,0.f}, a2 = {0.f,0.f,0.f,0.f};
            // input projection: A = pre-swizzled wih frags (L2-resident stream)
#pragma unroll
            for (int ss = 0; ss < 8; ss++) {
                const size_t e = wbase + (size_t)(w * 8 + ss) * 64;
                bf16x8 ah = *(const bf16x8*)(wih_hi + e * 8);
                bf16x8 al = *(const bf16x8*)(wih_lo + e * 8);
                a0 = __builtin_amdgcn_mfma_f32_16x16x32_bf16(ah, xh8[ss].v, a0, 0, 0, 0);
                a1 = __builtin_amdgcn_mfma_f32_16x16x32_bf16(al, xh8[ss].v, a1, 0, 0, 0);
                a2 = __builtin_amdgcn_mfma_f32_16x16x32_bf16(ah, xl8[ss].v, a2, 0, 0, 0);
            }
            // recurrent: A = LDS Whh1
#pragma unroll
            for (int ss = 0; ss < 8; ss++) {
                const int s32 = w * 8 + ss;
                const int off = lb * 2048 + (((s32 * 4 + hi4) ^ xr) << 4);
                bf16x8 ah = *(const bf16x8*)(W1hi + off);
                bf16x8 al = *(const bf16x8*)(W1lo + off);
                a0 = __builtin_amdgcn_mfma_f32_16x16x32_bf16(ah, yh8[ss].v, a0, 0, 0, 0);
                a1 = __builtin_amdgcn_mfma_f32_16x16x32_bf16(al, yh8[ss].v, a1, 0, 0, 0);
                a2 = __builtin_amdgcn_mfma_f32_16x16x32_bf16(ah, yl8[ss].v, a2, 0, 0, 0);
            }
            f32x4 v1 = a0 + a1 + a2;
            *(f32x4*)&Pw[((1 * 4 + w) * 64 + l) * 4] = v1;
        }
        __syncthreads();

        if (tid < 64) {
            // D layout: Pw[(lay*4+w)*64 + ll][jw] = D[c=(ll>>4)*4+jw][b=ll&15].
            if (actL0) {
                float pre[4];
#pragma unroll
                for (int g = 0; g < 4; g++) {
                    const int ll = (g << 4) | lb;
                    pre[g] = Pw[((0 * 4 + 0) * 64 + ll) * 4 + hi4]
                           + Pw[((0 * 4 + 1) * 64 + ll) * 4 + hi4]
                           + Pw[((0 * 4 + 2) * 64 + ll) * 4 + hi4]
                           + Pw[((0 * 4 + 3) * 64 + ll) * 4 + hi4];
                }
                const float ig = 1.f / (1.f + __expf(-(pre[0] + g00)));
                const float fg = 1.f / (1.f + __expf(-(pre[1] + g01)));
                const float gt = tanhf(pre[2] + g02);
                const float og = 1.f / (1.f + __expf(-(pre[3] + g03)));
                c0r = fg * c0r + ig * gt;
                const float hv = og * tanhf(c0r);
                if (s == SEQ - 1) {
                    h_tail[lb * HIDDEN + j0 + hi4] = hv;
                    c_tail[lb * HIDDEN + j0 + hi4] = c0r;
                }
                float q0 = __shfl(hv, 0 + l), q1 = __shfl(hv, 16 + l);
                float q2 = __shfl(hv, 32 + l), q3 = __shfl(hv, 48 + l);
                if (l < 16) {
                    u32 hb0 = f2bf(q0), hb1 = f2bf(q1), hb2 = f2bf(q2), hb3 = f2bf(q3);
                    u64 hq = (u64)(hb0 | (hb1 << 16)) | ((u64)(hb2 | (hb3 << 16)) << 32);
                    u32 lb0 = f2bf(q0 - bf2f(hb0)), lb1 = f2bf(q1 - bf2f(hb1));
                    u32 lb2 = f2bf(q2 - bf2f(hb2)), lb3 = f2bf(q3 - bf2f(hb3));
                    u64 lq = (u64)(lb0 | (lb1 << 16)) | ((u64)(lb2 | (lb3 << 16)) << 32);
                    const int iq = (s + 1) * 4096 + l * 256 + bid;
                    astore((u64*)seq0 + iq, hq);
                    astore((u64*)(seq0 + SEQ_LOU16) + iq, lq);
                }
            }
            if (actL1) {
                float pre[4];
#pragma unroll
                for (int g = 0; g < 4; g++) {
                    const int ll = (g << 4) | lb;
                    pre[g] = Pw[((1 * 4 + 0) * 64 + ll) * 4 + hi4]
                           + Pw[((1 * 4 + 1) * 64 + ll) * 4 + hi4]
                           + Pw[((1 * 4 + 2) * 64 + ll) * 4 + hi4]
                           + Pw[((1 * 4 + 3) * 64 + ll) * 4 + hi4];
                }
                const float ig = 1.f / (1.f + __expf(-(pre[0] + g10)));
                const float fg = 1.f / (1.f + __expf(-(pre[1] + g11)));
                const float gt = tanhf(pre[2] + g12);
                const float og = 1.f / (1.f + __expf(-(pre[3] + g13)));
                c1r = fg * c1r + ig * gt;
                const float hv = og * tanhf(c1r);
                if (s == SEQ) {
                    h_tail[16384 + lb * HIDDEN + j0 + hi4] = hv;
                    c_tail[16384 + lb * HIDDEN + j0 + hi4] = c1r;
                }
                float q0 = __shfl(hv, 0 + l), q1 = __shfl(hv, 16 + l);
                float q2 = __shfl(hv, 32 + l), q3 = __shfl(hv, 48 + l);
                if (l < 16) {
                    u32 hb0 = f2bf(q0), hb1 = f2bf(q1), hb2 = f2bf(q2), hb3 = f2bf(q3);
                    u64 hq = (u64)(hb0 | (hb1 << 16)) | ((u64)(hb2 | (hb3 << 16)) << 32);
                    u32 lb0 = f2bf(q0 - bf2f(hb0)), lb1 = f2bf(q1 - bf2f(hb1));
                    u32 lb2 = f2bf(q2 - bf2f(hb2)), lb3 = f2bf(q3 - bf2f(hb3));
                    u64 lq = (u64)(lb0 | (lb1 << 16)) | ((u64)(lb2 | (lb3 << 16)) << 32);
                    const int iq = s * 4096 + l * 256 + bid;
                    astore((u64*)seq1 + iq, hq);
                    astore((u64*)(seq1 + SEQ_LOU16) + iq, lq);
                }
            }
        }

        if (s < SEQ) {
            if (tid < 64) {
                asm volatile("s_waitcnt vmcnt(0)" ::: "memory");  // drain publishes
                if (tid == 0)
                    __hip_atomic_store(&arrive[bid], (u32)(s + 1), __ATOMIC_RELAXED,
                                       __HIP_MEMORY_SCOPE_AGENT);
                // off critical path: prefetch next step's G0 gates
                if (s + 1 < SEQ) {
                    const float* gp = G0 + (size_t)((s + 1) * BATCH + lb) * GATES + j0 + hi4;
                    g00 = gp[0]; g01 = gp[HIDDEN];
                    g02 = gp[2 * HIDDEN]; g03 = gp[3 * HIDDEN];
                }
                const u32 epoch = (u32)(s + 1);
                const int i0 = l * 4;
                for (;;) {
                    u32 q0 = __hip_atomic_load(&arrive[i0 + 0], __ATOMIC_RELAXED,
                                               __HIP_MEMORY_SCOPE_AGENT);
                    u32 q1 = __hip_atomic_load(&arrive[i0 + 1], __ATOMIC_RELAXED,
                                               __HIP_MEMORY_SCOPE_AGENT);
                    u32 q2 = __hip_atomic_load(&arrive[i0 + 2], __ATOMIC_RELAXED,
                                               __HIP_MEMORY_SCOPE_AGENT);
                    u32 q3 = __hip_atomic_load(&arrive[i0 + 3], __ATOMIC_RELAXED,
                                               __HIP_MEMORY_SCOPE_AGENT);
                    u32 m01 = q0 < q1 ? q0 : q1;
                    u32 m23 = q2 < q3 ? q2 : q3;
                    u32 mn = m01 < m23 ? m01 : m23;
                    if (__all(mn >= epoch)) break;
                    __builtin_amdgcn_s_sleep(2);
                }
                asm volatile("" ::: "memory");   // compiler barrier only
            }
            __syncthreads();
        }
    }
}

// ---------------- init & tails ----------------
__global__ void init_state(const float* __restrict__ h0, u16* __restrict__ seq0,
                           u16* __restrict__ seq1, u32* __restrict__ arrive) {
    int gid = blockIdx.x * 256 + threadIdx.x;  // 32768 = 2*16*1024
    if (gid < 256) arrive[gid] = 0;
    int layer = gid >> 14, b = (gid >> 10) & 15, j = gid & 1023;
    float h = h0[gid];
    u32 hb = f2bf(h);
    u32 lbits = f2bf(h - bf2f(hb));
    u16* sq = layer ? seq1 : seq0;
    sq[b * 1024 + j] = (u16)hb;                 // slot 0 hi
    sq[SEQ_LOU16 + b * 1024 + j] = (u16)lbits;  // slot 0 lo
}

__global__ void write_tails(const float* __restrict__ h_tail, const float* __restrict__ c_tail,
                            float* __restrict__ out) {
    int gid = blockIdx.x * 256 + threadIdx.x;  // 32768
    out[LOGITS_SZ + gid] = h_tail[gid];
    out[LOGITS_SZ + 32768 + gid] = c_tail[gid];
}

// ---------------- launch ----------------
extern "C" void kernel_launch(void* const* d_in, const int* in_sizes, int n_in,
                              void* d_out, int out_size, void* d_ws, size_t ws_size,
                              hipStream_t stream) {
    const int* x = (const int*)d_in[0];
    const float* h0 = (const float*)d_in[1];
    const float* c0 = (const float*)d_in[2];
    const float* emb = (const float*)d_in[3];
    const float* W_ih0 = (const float*)d_in[4];
    const float* W_hh0 = (const float*)d_in[5];
    const float* b_ih0 = (const float*)d_in[6];
    const float* b_hh0 = (const float*)d_in[7];
    const float* W_ih1 = (const float*)d_in[8];
    const float* W_hh1 = (const float*)d_in[9];
    const float* b_ih1 = (const float*)d_in[10];
    const float* b_hh1 = (const float*)d_in[11];
    const float* fc_W = (const float*)d_in[12];
    const float* fc_b = (const float*)d_in[13];
    float* out = (float*)d_out;
    float* ws = (float*)d_ws;

    // workspace layout (float offsets)
    const size_t OFF_G = 0;                                   // G0; later fc_W bf16
    const size_t OFF_X0H = OFF_G + (size_t)MROWS * GATES;     // u16 [4096][512]
    const size_t OFF_X0L = OFF_X0H + (size_t)MROWS * EMBED / 2;
    const size_t OFF_SEQ0 = OFF_X0L + (size_t)MROWS * EMBED / 2;
    const size_t SEQ_FLOATS = (size_t)2 * NSLOT * SEQ_SLOTU16 / 2;
    const size_t OFF_SEQ1 = OFF_SEQ0 + SEQ_FLOATS;
    const size_t OFF_WIHH = OFF_SEQ1 + SEQ_FLOATS;            // wih1 frag-order hi
    const size_t OFF_WIHL = OFF_WIHH + (size_t)GATES * HIDDEN / 2;
    const size_t OFF_W0H = OFF_WIHL + (size_t)GATES * HIDDEN / 2;  // wih0 hi
    const size_t OFF_W0L = OFF_W0H + (size_t)GATES * EMBED / 2;
    const size_t OFF_HT = OFF_W0L + (size_t)GATES * EMBED / 2;
    const size_t OFF_CT = OFF_HT + 2 * BATCH * HIDDEN;
    const size_t OFF_AR = OFF_CT + 2 * BATCH * HIDDEN;

    u16* x0H = (u16*)(ws + OFF_X0H);
    u16* x0L = (u16*)(ws + OFF_X0L);
    u16* seq0 = (u16*)(ws + OFF_SEQ0);
    u16* seq1 = (u16*)(ws + OFF_SEQ1);
    u16* wihH = (u16*)(ws + OFF_WIHH);
    u16* wihL = (u16*)(ws + OFF_WIHL);
    u16* w0H = (u16*)(ws + OFF_W0H);
    u16* w0L = (u16*)(ws + OFF_W0L);
    u32* arrive = (u32*)(ws + OFF_AR);

    init_state<<<128, 256, 0, stream>>>(h0, seq0, seq1, arrive);
    embed_hl_kernel<<<MROWS, 128, 0, stream>>>(x, emb, x0H, x0L);
    wih_swizzle_kernel<<<256, 256, 0, stream>>>(W_ih1, wihH, wihL);
    f32_to_bf16hl_kernel<<<2048, 256, 0, stream>>>(W_ih0, w0H, w0L, GATES * EMBED / 4);

    // layer-0 input projection via split-precision MFMA (includes both L0 biases)
    xproj_mfma<<<dim3(GATES / 128, MROWS / 128), 256, 0, stream>>>(
        x0H, x0L, w0H, w0L, b_ih0, b_hh0, ws + OFF_G);

    // fused balanced pipelined recurrence (both layers) — R9-proven kernel
    {
        const float* Whh0p = W_hh0;
        const float* Whh1p = W_hh1;
        const float* Gp = ws + OFF_G;
        const u16* wh = wihH;
        const u16* wl = wihL;
        const float* bi = b_ih1;
        const float* bh = b_hh1;
        const float* ci = c0;
        float* ct = ws + OFF_CT;
        float* ht = ws + OFF_HT;
        u16* s0 = seq0;
        u16* s1 = seq1;
        u32* ar = arrive;
        void* args[] = {(void*)&Whh0p, (void*)&Whh1p, (void*)&Gp, (void*)&wh,
                        (void*)&wl, (void*)&bi, (void*)&bh, (void*)&ci,
                        (void*)&ct, (void*)&ht, (void*)&s0, (void*)&s1, (void*)&ar};
        hipLaunchCooperativeKernel((void*)lstm_fused, dim3(256), dim3(256), args, 0, stream);
    }

    // FC via bf16 MFMA: A = seq1 hi slots 1..256 directly; B = fc_W bf16 (G0 dead)
    f32_to_bf16_kernel<<<4096, 256, 0, stream>>>(fc_W, (u16*)(ws + OFF_G), VOCAB * HIDDEN / 8);
    fc_mfma<<<dim3(VOCAB / 128, MROWS / 128), 256, 0, stream>>>(
        seq1 + SEQ_SLOTU16, (const u16*)(ws + OFF_G), fc_b, out);

    write_tails<<<128, 256, 0, stream>>>(ws + OFF_HT, ws + OFF_CT, out);
}

// Round 13
// 3835.496 us; speedup vs baseline: 1.5477x; 1.0076x over previous
//
#include <hip/hip_runtime.h>
#include <hip/hip_bf16.h>
#include <cmath>

// Problem constants
#define BATCH 16
#define SEQ 256
#define EMBED 512
#define HIDDEN 1024
#define GATES 4096       // 4*HIDDEN
#define VOCAB 32000
#define MROWS 4096       // BATCH*SEQ
#define LOGITS_SZ 131072000  // 16*256*32000

#define NSLOT 257                    // h-history slots (init + 256 steps)
#define SEQ_SLOTU16 16384            // u16 per slot: 16 batch x 1024
#define SEQ_LOU16 (NSLOT * SEQ_SLOTU16)

typedef unsigned int u32;
typedef unsigned short u16;
typedef unsigned long long u64;
typedef __attribute__((ext_vector_type(8))) short bf16x8;
typedef __attribute__((ext_vector_type(4))) float f32x4;

#define AS1 __attribute__((address_space(1)))
#define AS3 __attribute__((address_space(3)))

// ---------------- helpers ----------------
__device__ __forceinline__ u32 f2bf(float f) {          // RNE fp32->bf16 (bits)
    u32 u = __float_as_uint(f);
    return (u + 0x7fffu + ((u >> 16) & 1u)) >> 16;
}
__device__ __forceinline__ float bf2f(u32 b) { return __uint_as_float(b << 16); }

__device__ __forceinline__ void astore(u64* p, u64 v) {
    __hip_atomic_store(p, v, __ATOMIC_RELAXED, __HIP_MEMORY_SCOPE_AGENT);
}

// ---------------- embedding gather -> bf16 hi/lo planes ----------------
__global__ void embed_hl_kernel(const int* __restrict__ x, const float* __restrict__ emb,
                                u16* __restrict__ XH, u16* __restrict__ XL) {
    int r = blockIdx.x;            // r = s*16 + b
    int s = r >> 4, b = r & 15;
    int tok = x[b * SEQ + s];
    const float4* src = (const float4*)(emb + (size_t)tok * EMBED);
    int i = threadIdx.x;           // 0..127, 4 elems each
    float4 a = src[i];
    u32 h0 = f2bf(a.x), h1 = f2bf(a.y), h2 = f2bf(a.z), h3 = f2bf(a.w);
    u64 hq = (u64)(h0 | (h1 << 16)) | ((u64)(h2 | (h3 << 16)) << 32);
    u32 l0 = f2bf(a.x - bf2f(h0)), l1 = f2bf(a.y - bf2f(h1));
    u32 l2 = f2bf(a.z - bf2f(h2)), l3 = f2bf(a.w - bf2f(h3));
    u64 lq = (u64)(l0 | (l1 << 16)) | ((u64)(l2 | (l3 << 16)) << 32);
    ((u64*)(XH + (size_t)r * EMBED))[i] = hq;
    ((u64*)(XL + (size_t)r * EMBED))[i] = lq;
}

// ---------------- fp32 -> bf16 conversion (hi only, for fc_W) ----------------
__global__ __launch_bounds__(256) void f32_to_bf16_kernel(
    const float* __restrict__ in, u16* __restrict__ out, int n8) {
    for (int i = blockIdx.x * 256 + threadIdx.x; i < n8; i += gridDim.x * 256) {
        float4 a = ((const float4*)in)[2 * (size_t)i + 0];
        float4 b = ((const float4*)in)[2 * (size_t)i + 1];
        uint4 o;
        o.x = f2bf(a.x) | (f2bf(a.y) << 16);
        o.y = f2bf(a.z) | (f2bf(a.w) << 16);
        o.z = f2bf(b.x) | (f2bf(b.y) << 16);
        o.w = f2bf(b.z) | (f2bf(b.w) << 16);
        ((uint4*)out)[i] = o;
    }
}

// ---------------- fp32 -> bf16 hi+lo split ----------------
__global__ __launch_bounds__(256) void f32_to_bf16hl_kernel(
    const float* __restrict__ in, u16* __restrict__ hi, u16* __restrict__ lo, int n4) {
    for (int i = blockIdx.x * 256 + threadIdx.x; i < n4; i += gridDim.x * 256) {
        float4 a = ((const float4*)in)[i];
        u32 h0 = f2bf(a.x), h1 = f2bf(a.y), h2 = f2bf(a.z), h3 = f2bf(a.w);
        u64 hq = (u64)(h0 | (h1 << 16)) | ((u64)(h2 | (h3 << 16)) << 32);
        u32 l0 = f2bf(a.x - bf2f(h0)), l1 = f2bf(a.y - bf2f(h1));
        u32 l2 = f2bf(a.z - bf2f(h2)), l3 = f2bf(a.w - bf2f(h3));
        u64 lq = (u64)(l0 | (l1 << 16)) | ((u64)(l2 | (l3 << 16)) << 32);
        ((u64*)hi)[i] = hq;
        ((u64*)lo)[i] = lq;
    }
}

// ---------------- W_ih1 pre-swizzle into MFMA fragment order ----------------
__global__ __launch_bounds__(256) void wih_swizzle_kernel(
    const float* __restrict__ W, u16* __restrict__ hi, u16* __restrict__ lo) {
    int bid = blockIdx.x, tid = threadIdx.x;
    int j0 = bid * 4;
#pragma unroll
    for (int i = 0; i < 8; i++) {
        int q = i * 256 + tid;           // 0..2047
        int s32 = q >> 6, l = q & 63;
        int row = l & 15, hi4 = l >> 4;
        int nrow = (row >> 2) * HIDDEN + j0 + (row & 3);
        int k = s32 * 32 + hi4 * 8;
        const float* src = W + (size_t)nrow * HIDDEN + k;
        u32 hw[4], lw[4];
#pragma unroll
        for (int e = 0; e < 4; e++) {
            float x0 = src[2 * e], x1 = src[2 * e + 1];
            u32 h0 = f2bf(x0), h1 = f2bf(x1);
            hw[e] = h0 | (h1 << 16);
            lw[e] = f2bf(x0 - bf2f(h0)) | (f2bf(x1 - bf2f(h1)) << 16);
        }
        size_t e0 = (size_t)bid * 2048 + q;
        ((uint4*)hi)[e0] = make_uint4(hw[0], hw[1], hw[2], hw[3]);
        ((uint4*)lo)[e0] = make_uint4(lw[0], lw[1], lw[2], lw[3]);
    }
}

// ---------------- split-precision MFMA input projection (layer 0) ----------
// G0[r][n] = sum_k X[r][k]*Wih0[n][k] + b1[n] + b2[n], via hi/lo 3-chain MFMA.
// XCD-aware bijective block swizzle (nwg=1024, 1024%8==0) — pure block remap.
__global__ __launch_bounds__(256) void xproj_mfma(
    const u16* __restrict__ Ahi, const u16* __restrict__ Alo,   // [MROWS][512]
    const u16* __restrict__ Bhi, const u16* __restrict__ Blo,   // [4096][512]
    const float* __restrict__ b1, const float* __restrict__ b2,
    float* __restrict__ C) {                                    // [MROWS][4096]
    const int K = EMBED;           // 512
    const int N = GATES;
    __shared__ char smem[32768];
    char* AsH = smem;
    char* AsL = smem + 8192;
    char* BsH = smem + 16384;
    char* BsL = smem + 24576;

    int tid = threadIdx.x;
    int w = tid >> 6, l = tid & 63;
    int lin = blockIdx.y * gridDim.x + blockIdx.x;   // [0,1024)
    int swz = (lin & 7) * 128 + (lin >> 3);          // bijective XCD chunks
    int bn = swz % 32, bm = swz / 32;
    int wr = w >> 1, wc = w & 1;
    int lr = l & 15, lk = l >> 4;

    f32x4 acc[4][4];
#pragma unroll
    for (int m = 0; m < 4; m++)
#pragma unroll
        for (int n = 0; n < 4; n++) acc[m][n] = {0.f, 0.f, 0.f, 0.f};

    int srow = tid >> 2, skc = (tid & 3) * 8;
    const u16* gah0 = Ahi + (size_t)(bm * 128 + srow) * K + skc;
    const u16* gah1 = Ahi + (size_t)(bm * 128 + 64 + srow) * K + skc;
    const u16* gal0 = Alo + (size_t)(bm * 128 + srow) * K + skc;
    const u16* gal1 = Alo + (size_t)(bm * 128 + 64 + srow) * K + skc;
    const u16* gbh0 = Bhi + (size_t)(bn * 128 + srow) * K + skc;
    const u16* gbh1 = Bhi + (size_t)(bn * 128 + 64 + srow) * K + skc;
    const u16* gbl0 = Blo + (size_t)(bn * 128 + srow) * K + skc;
    const u16* gbl1 = Blo + (size_t)(bn * 128 + 64 + srow) * K + skc;
    char* lah0 = AsH + w * 1024;       char* lah1 = AsH + 4096 + w * 1024;
    char* lal0 = AsL + w * 1024;       char* lal1 = AsL + 4096 + w * 1024;
    char* lbh0 = BsH + w * 1024;       char* lbh1 = BsH + 4096 + w * 1024;
    char* lbl0 = BsL + w * 1024;       char* lbl1 = BsL + 4096 + w * 1024;

    int afo[4], bfo[4];
#pragma unroll
    for (int m = 0; m < 4; m++) afo[m] = (wr * 64 + m * 16 + lr) * 64 + lk * 16;
#pragma unroll
    for (int n = 0; n < 4; n++) bfo[n] = (wc * 64 + n * 16 + lr) * 64 + lk * 16;

    for (int k0 = 0; k0 < K; k0 += 32) {
        __syncthreads();
        __builtin_amdgcn_global_load_lds((const AS1 u32*)(const void*)(gah0 + k0),
                                         (AS3 u32*)(void*)lah0, 16, 0, 0);
        __builtin_amdgcn_global_load_lds((const AS1 u32*)(const void*)(gah1 + k0),
                                         (AS3 u32*)(void*)lah1, 16, 0, 0);
        __builtin_amdgcn_global_load_lds((const AS1 u32*)(const void*)(gal0 + k0),
                                         (AS3 u32*)(void*)lal0, 16, 0, 0);
        __builtin_amdgcn_global_load_lds((const AS1 u32*)(const void*)(gal1 + k0),
                                         (AS3 u32*)(void*)lal1, 16, 0, 0);
        __builtin_amdgcn_global_load_lds((const AS1 u32*)(const void*)(gbh0 + k0),
                                         (AS3 u32*)(void*)lbh0, 16, 0, 0);
        __builtin_amdgcn_global_load_lds((const AS1 u32*)(const void*)(gbh1 + k0),
                                         (AS3 u32*)(void*)lbh1, 16, 0, 0);
        __builtin_amdgcn_global_load_lds((const AS1 u32*)(const void*)(gbl0 + k0),
                                         (AS3 u32*)(void*)lbl0, 16, 0, 0);
        __builtin_amdgcn_global_load_lds((const AS1 u32*)(const void*)(gbl1 + k0),
                                         (AS3 u32*)(void*)lbl1, 16, 0, 0);
        __syncthreads();

        bf16x8 ah[4], al[4], bh[4], bl[4];
#pragma unroll
        for (int m = 0; m < 4; m++) {
            ah[m] = *(const bf16x8*)(AsH + afo[m]);
            al[m] = *(const bf16x8*)(AsL + afo[m]);
        }
#pragma unroll
        for (int n = 0; n < 4; n++) {
            bh[n] = *(const bf16x8*)(BsH + bfo[n]);
            bl[n] = *(const bf16x8*)(BsL + bfo[n]);
        }
#pragma unroll
        for (int m = 0; m < 4; m++)
#pragma unroll
            for (int n = 0; n < 4; n++) {
                acc[m][n] = __builtin_amdgcn_mfma_f32_16x16x32_bf16(ah[m], bh[n], acc[m][n], 0, 0, 0);
                acc[m][n] = __builtin_amdgcn_mfma_f32_16x16x32_bf16(al[m], bh[n], acc[m][n], 0, 0, 0);
                acc[m][n] = __builtin_amdgcn_mfma_f32_16x16x32_bf16(ah[m], bl[n], acc[m][n], 0, 0, 0);
            }
    }

    int rbase = bm * 128 + wr * 64 + lk * 4;
    int cbase = bn * 128 + wc * 64 + lr;
#pragma unroll
    for (int m = 0; m < 4; m++) {
#pragma unroll
        for (int n = 0; n < 4; n++) {
            int c = cbase + n * 16;
            float bb = b1[c] + b2[c];
#pragma unroll
            for (int j = 0; j < 4; j++) {
                int r = rbase + m * 16 + j;
                C[(size_t)r * N + c] = acc[m][n][j] + bb;
            }
        }
    }
}

// ---------------- bf16 MFMA FC GEMM (XCD-swizzled block mapping) ------------
__global__ __launch_bounds__(256) void fc_mfma(
    const u16* __restrict__ Abf,   // [MROWS][1024] bf16
    const u16* __restrict__ Bbf,   // [VOCAB][1024] bf16
    const float* __restrict__ bias,
    float* __restrict__ C) {
    const int K = HIDDEN;
    const int N = VOCAB;
    __shared__ char smem[16384];
    char* As = smem;
    char* Bs = smem + 8192;

    int tid = threadIdx.x;
    int w = tid >> 6, l = tid & 63;
    // XCD-aware bijective swizzle (T1): nwg = 250*32 = 8000, 8000 % 8 == 0.
    // XCD k owns tiles [k*1000,(k+1)*1000): A-panels L2-resident, B reused 4x.
    int lin = blockIdx.y * gridDim.x + blockIdx.x;
    int swz = (lin & 7) * 1000 + (lin >> 3);
    int bn = swz % 250, bm = swz / 250;
    int wr = w >> 1, wc = w & 1;
    int lr = l & 15, lk = l >> 4;

    f32x4 acc[4][4];
#pragma unroll
    for (int m = 0; m < 4; m++)
#pragma unroll
        for (int n = 0; n < 4; n++) acc[m][n] = {0.f, 0.f, 0.f, 0.f};

    int srow = tid >> 2, skc = (tid & 3) * 8;
    const u16* ga0 = Abf + (size_t)(bm * 128 + srow) * K + skc;
    const u16* ga1 = Abf + (size_t)(bm * 128 + 64 + srow) * K + skc;
    const u16* gb0 = Bbf + (size_t)(bn * 128 + srow) * K + skc;
    const u16* gb1 = Bbf + (size_t)(bn * 128 + 64 + srow) * K + skc;
    char* la0 = As + w * 1024;
    char* la1 = As + 4096 + w * 1024;
    char* lb0 = Bs + w * 1024;
    char* lb1 = Bs + 4096 + w * 1024;

    int afo[4], bfo[4];
#pragma unroll
    for (int m = 0; m < 4; m++) afo[m] = (wr * 64 + m * 16 + lr) * 64 + lk * 16;
#pragma unroll
    for (int n = 0; n < 4; n++) bfo[n] = (wc * 64 + n * 16 + lr) * 64 + lk * 16;

    for (int k0 = 0; k0 < K; k0 += 32) {
        __syncthreads();
        __builtin_amdgcn_global_load_lds((const AS1 u32*)(const void*)(ga0 + k0),
                                         (AS3 u32*)(void*)la0, 16, 0, 0);
        __builtin_amdgcn_global_load_lds((const AS1 u32*)(const void*)(ga1 + k0),
                                         (AS3 u32*)(void*)la1, 16, 0, 0);
        __builtin_amdgcn_global_load_lds((const AS1 u32*)(const void*)(gb0 + k0),
                                         (AS3 u32*)(void*)lb0, 16, 0, 0);
        __builtin_amdgcn_global_load_lds((const AS1 u32*)(const void*)(gb1 + k0),
                                         (AS3 u32*)(void*)lb1, 16, 0, 0);
        __syncthreads();

        bf16x8 af[4], bfr[4];
#pragma unroll
        for (int m = 0; m < 4; m++) af[m] = *(const bf16x8*)(As + afo[m]);
#pragma unroll
        for (int n = 0; n < 4; n++) bfr[n] = *(const bf16x8*)(Bs + bfo[n]);
#pragma unroll
        for (int m = 0; m < 4; m++)
#pragma unroll
            for (int n = 0; n < 4; n++)
                acc[m][n] = __builtin_amdgcn_mfma_f32_16x16x32_bf16(
                    af[m], bfr[n], acc[m][n], 0, 0, 0);
    }

    int rbase = bm * 128 + wr * 64 + lk * 4;
    int cbase = bn * 128 + wc * 64 + lr;
#pragma unroll
    for (int m = 0; m < 4; m++) {
#pragma unroll
        for (int n = 0; n < 4; n++) {
            int c = cbase + n * 16;
            float bb = bias[c];
#pragma unroll
            for (int j = 0; j < 4; j++) {
                int r = rbase + m * 16 + j;
                int orow = (r & 15) * SEQ + (r >> 4);   // [B,S,V] layout
                C[(size_t)orow * N + c] = acc[m][n][j] + bb;
            }
        }
    }
}

// ---------------- fused balanced 2-layer persistent LSTM (R11-proven) --------
// 256 blocks x 256 threads. EVERY block owns 4 L0 units AND 4 L1 units.
// Step s: L0 computes t=s, L1 computes t=s-1; both consume seq0 slot s.
// Whh0/Whh1 hi/lo in LDS; W_ih1 STREAMED from L2 in pre-swizzled fragment
// order (register-resident variant miscompiles/corrupts — R10/R12 bisect;
// do NOT re-attempt). Unified wave-0 tail, single-wave vmcnt->arrive->poll.
__global__ __launch_bounds__(256, 1) void lstm_fused(
    const float* __restrict__ Whh0, const float* __restrict__ Whh1,
    const float* __restrict__ G0,        // [4096][4096] rows t*16+b (L0 x-proj + biases)
    const u16* __restrict__ wih_hi,      // pre-swizzled [256][2048] x 16B
    const u16* __restrict__ wih_lo,
    const float* __restrict__ bi1, const float* __restrict__ bh1,
    const float* __restrict__ c0in,      // [2][16][1024]
    float* __restrict__ c_tail, float* __restrict__ h_tail,  // [2][16][1024]
    u16* __restrict__ seq0, u16* __restrict__ seq1,          // [NSLOT hi | NSLOT lo]
    u32* __restrict__ arrive) {
    __shared__ __align__(16) char lds[139264];
    char* W0hi = lds;                   // [16 rows][2048B] swizzled Whh0 hi
    char* W0lo = lds + 32768;
    char* W1hi = lds + 65536;
    char* W1lo = lds + 98304;
    float* Pw = (float*)(lds + 131072); // [2 layer][4 wave][64 lane][4] = 8 KB

    const int tid = threadIdx.x;
    const int bid = blockIdx.x;
    const int j0 = bid * 4;                  // 4 units per layer per block
    const int w = tid >> 6, l = tid & 63;
    const int lb = l & 15, hi4 = l >> 4, xr = l & 7;

    // ---- one-time: stage Whh0/Whh1 slices (16 gate-cols x 1024) hi/lo ----
#pragma unroll
    for (int lay = 0; lay < 2; lay++) {
        const float* Whh = lay ? Whh1 : Whh0;
        char* dH = lay ? W1hi : W0hi;
        char* dL = lay ? W1lo : W0lo;
        for (int i = 0; i < 8; i++) {
            int q = i * 256 + tid;            // 16B chunk id 0..2047
            int row = q >> 7, cin = q & 127;  // row = gate-col (0..15)
            int nrow = (row >> 2) * HIDDEN + j0 + (row & 3);
            const float* src = Whh + (size_t)nrow * HIDDEN + cin * 8;
            int dst = row * 2048 + ((cin ^ (row & 7)) << 4);
            u32 hw[4], lw[4];
#pragma unroll
            for (int e = 0; e < 4; e++) {
                float x0 = src[2 * e], x1 = src[2 * e + 1];
                u32 hb0 = f2bf(x0), hb1 = f2bf(x1);
                hw[e] = hb0 | (hb1 << 16);
                lw[e] = f2bf(x0 - bf2f(hb0)) | (f2bf(x1 - bf2f(hb1)) << 16);
            }
            *(uint4*)(dH + dst) = make_uint4(hw[0], hw[1], hw[2], hw[3]);
            *(uint4*)(dL + dst) = make_uint4(lw[0], lw[1], lw[2], lw[3]);
        }
    }

    // pointwise state (wave 0): lane l -> batch lb, unit jj = hi4 (one per layer)
    float c0r = 0.f, c1r = 0.f;
    float g00 = 0, g01 = 0, g02 = 0, g03 = 0;   // L0 gates (prefetched from G0)
    float g10 = 0, g11 = 0, g12 = 0, g13 = 0;   // L1 gates (constant biases)
    if (tid < 64) {
        c0r = c0in[lb * HIDDEN + j0 + hi4];
        c1r = c0in[16384 + lb * HIDDEN + j0 + hi4];
        const float* gp = G0 + (size_t)lb * GATES + j0 + hi4;   // t = 0
        g00 = gp[0]; g01 = gp[HIDDEN]; g02 = gp[2 * HIDDEN]; g03 = gp[3 * HIDDEN];
        g10 = bi1[j0 + hi4] + bh1[j0 + hi4];
        g11 = bi1[HIDDEN + j0 + hi4] + bh1[HIDDEN + j0 + hi4];
        g12 = bi1[2 * HIDDEN + j0 + hi4] + bh1[2 * HIDDEN + j0 + hi4];
        g13 = bi1[3 * HIDDEN + j0 + hi4] + bh1[3 * HIDDEN + j0 + hi4];
    }
    __syncthreads();

    const u64* s0h = (const u64*)seq0;
    const u64* s0l = (const u64*)(seq0 + SEQ_LOU16);
    const u64* s1h = (const u64*)seq1;
    const u64* s1l = (const u64*)(seq1 + SEQ_LOU16);
    const int fb = lb * 256 + hi4 * 2;            // u64 base within a slot
    const size_t wbase = (size_t)bid * 2048 + l;  // wih fragment entry base

    union u4bf { uint4 u; bf16x8 v; };

    for (int s = 0; s <= SEQ; s++) {
        const bool actL0 = (s < SEQ);
        const bool actL1 = (s >= 1);

        // ---- up-front loads (L2-shared within XCD) ----
        u4bf xh8[8], xl8[8], yh8[8], yl8[8];
        {
            const int base = s * 4096 + fb;
#pragma unroll
            for (int ss = 0; ss < 8; ss++) {
                const int idx = base + (w * 8 + ss) * 8;
                xh8[ss].u = *(const uint4*)(s0h + idx);
                xl8[ss].u = *(const uint4*)(s0l + idx);
            }
        }
        if (actL1) {
            const int base = (s - 1) * 4096 + fb;
#pragma unroll
            for (int ss = 0; ss < 8; ss++) {
                const int idx = base + (w * 8 + ss) * 8;
                yh8[ss].u = *(const uint4*)(s1h + idx);
                yl8[ss].u = *(const uint4*)(s1l + idx);
            }
        }

        if (actL0) {
            f32x4 a0 = {0.f,0.f,0.f,0.f}, a1 = {0.f,0.f,0.f,0.f}, a2 = {0.f,0.f,0.f,0.f};
#pragma unroll
            for (int ss = 0; ss < 8; ss++) {
                const int s32 = w * 8 + ss;
                const int off = lb * 2048 + (((s32 * 4 + hi4) ^ xr) << 4);
                bf16x8 ah = *(const bf16x8*)(W0hi + off);
                bf16x8 al = *(const bf16x8*)(W0lo + off);
                a0 = __builtin_amdgcn_mfma_f32_16x16x32_bf16(ah, xh8[ss].v, a0, 0, 0, 0);
                a1 = __builtin_amdgcn_mfma_f32_16x16x32_bf16(al, xh8[ss].v, a1, 0, 0, 0);
                a2 = __builtin_amdgcn_mfma_f32_16x16x32_bf16(ah, xl8[ss].v, a2, 0, 0, 0);
            }
            f32x4 v0 = a0 + a1 + a2;
            *(f32x4*)&Pw[((0 * 4 + w) * 64 + l) * 4] = v0;
        }

        if (actL1) {
            f32x4 a0 = {0.f,0.f,0.f,0.f}, a1 = {0.f,0.f,0.f,0.f}, a2 = {0.f,0.f,0.f,0.f};
            // input projection: A = pre-swizzled wih frags (L2-resident stream)
#pragma unroll
            for (int ss = 0; ss < 8; ss++) {
                const size_t e = wbase + (size_t)(w * 8 + ss) * 64;
                bf16x8 ah = *(const bf16x8*)(wih_hi + e * 8);
                bf16x8 al = *(const bf16x8*)(wih_lo + e * 8);
                a0 = __builtin_amdgcn_mfma_f32_16x16x32_bf16(ah, xh8[ss].v, a0, 0, 0, 0);
                a1 = __builtin_amdgcn_mfma_f32_16x16x32_bf16(al, xh8[ss].v, a1, 0, 0, 0);
                a2 = __builtin_amdgcn_mfma_f32_16x16x32_bf16(ah, xl8[ss].v, a2, 0, 0, 0);
            }
            // recurrent: A = LDS Whh1
#pragma unroll
            for (int ss = 0; ss < 8; ss++) {
                const int s32 = w * 8 + ss;
                const int off = lb * 2048 + (((s32 * 4 + hi4) ^ xr) << 4);
                bf16x8 ah = *(const bf16x8*)(W1hi + off);
                bf16x8 al = *(const bf16x8*)(W1lo + off);
                a0 = __builtin_amdgcn_mfma_f32_16x16x32_bf16(ah, yh8[ss].v, a0, 0, 0, 0);
                a1 = __builtin_amdgcn_mfma_f32_16x16x32_bf16(al, yh8[ss].v, a1, 0, 0, 0);
                a2 = __builtin_amdgcn_mfma_f32_16x16x32_bf16(ah, yl8[ss].v, a2, 0, 0, 0);
            }
            f32x4 v1 = a0 + a1 + a2;
            *(f32x4*)&Pw[((1 * 4 + w) * 64 + l) * 4] = v1;
        }
        __syncthreads();

        if (tid < 64) {
            // D layout: Pw[(lay*4+w)*64 + ll][jw] = D[c=(ll>>4)*4+jw][b=ll&15].
            if (actL0) {
                float pre[4];
#pragma unroll
                for (int g = 0; g < 4; g++) {
                    const int ll = (g << 4) | lb;
                    pre[g] = Pw[((0 * 4 + 0) * 64 + ll) * 4 + hi4]
                           + Pw[((0 * 4 + 1) * 64 + ll) * 4 + hi4]
                           + Pw[((0 * 4 + 2) * 64 + ll) * 4 + hi4]
                           + Pw[((0 * 4 + 3) * 64 + ll) * 4 + hi4];
                }
                const float ig = 1.f / (1.f + __expf(-(pre[0] + g00)));
                const float fg = 1.f / (1.f + __expf(-(pre[1] + g01)));
                const float gt = tanhf(pre[2] + g02);
                const float og = 1.f / (1.f + __expf(-(pre[3] + g03)));
                c0r = fg * c0r + ig * gt;
                const float hv = og * tanhf(c0r);
                if (s == SEQ - 1) {
                    h_tail[lb * HIDDEN + j0 + hi4] = hv;
                    c_tail[lb * HIDDEN + j0 + hi4] = c0r;
                }
                float q0 = __shfl(hv, 0 + l), q1 = __shfl(hv, 16 + l);
                float q2 = __shfl(hv, 32 + l), q3 = __shfl(hv, 48 + l);
                if (l < 16) {
                    u32 hb0 = f2bf(q0), hb1 = f2bf(q1), hb2 = f2bf(q2), hb3 = f2bf(q3);
                    u64 hq = (u64)(hb0 | (hb1 << 16)) | ((u64)(hb2 | (hb3 << 16)) << 32);
                    u32 lb0 = f2bf(q0 - bf2f(hb0)), lb1 = f2bf(q1 - bf2f(hb1));
                    u32 lb2 = f2bf(q2 - bf2f(hb2)), lb3 = f2bf(q3 - bf2f(hb3));
                    u64 lq = (u64)(lb0 | (lb1 << 16)) | ((u64)(lb2 | (lb3 << 16)) << 32);
                    const int iq = (s + 1) * 4096 + l * 256 + bid;
                    astore((u64*)seq0 + iq, hq);
                    astore((u64*)(seq0 + SEQ_LOU16) + iq, lq);
                }
            }
            if (actL1) {
                float pre[4];
#pragma unroll
                for (int g = 0; g < 4; g++) {
                    const int ll = (g << 4) | lb;
                    pre[g] = Pw[((1 * 4 + 0) * 64 + ll) * 4 + hi4]
                           + Pw[((1 * 4 + 1) * 64 + ll) * 4 + hi4]
                           + Pw[((1 * 4 + 2) * 64 + ll) * 4 + hi4]
                           + Pw[((1 * 4 + 3) * 64 + ll) * 4 + hi4];
                }
                const float ig = 1.f / (1.f + __expf(-(pre[0] + g10)));
                const float fg = 1.f / (1.f + __expf(-(pre[1] + g11)));
                const float gt = tanhf(pre[2] + g12);
                const float og = 1.f / (1.f + __expf(-(pre[3] + g13)));
                c1r = fg * c1r + ig * gt;
                const float hv = og * tanhf(c1r);
                if (s == SEQ) {
                    h_tail[16384 + lb * HIDDEN + j0 + hi4] = hv;
                    c_tail[16384 + lb * HIDDEN + j0 + hi4] = c1r;
                }
                float q0 = __shfl(hv, 0 + l), q1 = __shfl(hv, 16 + l);
                float q2 = __shfl(hv, 32 + l), q3 = __shfl(hv, 48 + l);
                if (l < 16) {
                    u32 hb0 = f2bf(q0), hb1 = f2bf(q1), hb2 = f2bf(q2), hb3 = f2bf(q3);
                    u64 hq = (u64)(hb0 | (hb1 << 16)) | ((u64)(hb2 | (hb3 << 16)) << 32);
                    u32 lb0 = f2bf(q0 - bf2f(hb0)), lb1 = f2bf(q1 - bf2f(hb1));
                    u32 lb2 = f2bf(q2 - bf2f(hb2)), lb3 = f2bf(q3 - bf2f(hb3));
                    u64 lq = (u64)(lb0 | (lb1 << 16)) | ((u64)(lb2 | (lb3 << 16)) << 32);
                    const int iq = s * 4096 + l * 256 + bid;
                    astore((u64*)seq1 + iq, hq);
                    astore((u64*)(seq1 + SEQ_LOU16) + iq, lq);
                }
            }
        }

        if (s < SEQ) {
            if (tid < 64) {
                asm volatile("s_waitcnt vmcnt(0)" ::: "memory");  // drain publishes
                if (tid == 0)
                    __hip_atomic_store(&arrive[bid], (u32)(s + 1), __ATOMIC_RELAXED,
                                       __HIP_MEMORY_SCOPE_AGENT);
                // off critical path: prefetch next step's G0 gates
                if (s + 1 < SEQ) {
                    const float* gp = G0 + (size_t)((s + 1) * BATCH + lb) * GATES + j0 + hi4;
                    g00 = gp[0]; g01 = gp[HIDDEN];
                    g02 = gp[2 * HIDDEN]; g03 = gp[3 * HIDDEN];
                }
                const u32 epoch = (u32)(s + 1);
                const int i0 = l * 4;
                for (;;) {
                    u32 q0 = __hip_atomic_load(&arrive[i0 + 0], __ATOMIC_RELAXED,
                                               __HIP_MEMORY_SCOPE_AGENT);
                    u32 q1 = __hip_atomic_load(&arrive[i0 + 1], __ATOMIC_RELAXED,
                                               __HIP_MEMORY_SCOPE_AGENT);
                    u32 q2 = __hip_atomic_load(&arrive[i0 + 2], __ATOMIC_RELAXED,
                                               __HIP_MEMORY_SCOPE_AGENT);
                    u32 q3 = __hip_atomic_load(&arrive[i0 + 3], __ATOMIC_RELAXED,
                                               __HIP_MEMORY_SCOPE_AGENT);
                    u32 m01 = q0 < q1 ? q0 : q1;
                    u32 m23 = q2 < q3 ? q2 : q3;
                    u32 mn = m01 < m23 ? m01 : m23;
                    if (__all(mn >= epoch)) break;
                    __builtin_amdgcn_s_sleep(2);
                }
                asm volatile("" ::: "memory");   // compiler barrier only
            }
            __syncthreads();
        }
    }
}

// ---------------- init & tails ----------------
__global__ void init_state(const float* __restrict__ h0, u16* __restrict__ seq0,
                           u16* __restrict__ seq1, u32* __restrict__ arrive) {
    int gid = blockIdx.x * 256 + threadIdx.x;  // 32768 = 2*16*1024
    if (gid < 256) arrive[gid] = 0;
    int layer = gid >> 14, b = (gid >> 10) & 15, j = gid & 1023;
    float h = h0[gid];
    u32 hb = f2bf(h);
    u32 lbits = f2bf(h - bf2f(hb));
    u16* sq = layer ? seq1 : seq0;
    sq[b * 1024 + j] = (u16)hb;                 // slot 0 hi
    sq[SEQ_LOU16 + b * 1024 + j] = (u16)lbits;  // slot 0 lo
}

__global__ void write_tails(const float* __restrict__ h_tail, const float* __restrict__ c_tail,
                            float* __restrict__ out) {
    int gid = blockIdx.x * 256 + threadIdx.x;  // 32768
    out[LOGITS_SZ + gid] = h_tail[gid];
    out[LOGITS_SZ + 32768 + gid] = c_tail[gid];
}

// ---------------- launch ----------------
extern "C" void kernel_launch(void* const* d_in, const int* in_sizes, int n_in,
                              void* d_out, int out_size, void* d_ws, size_t ws_size,
                              hipStream_t stream) {
    const int* x = (const int*)d_in[0];
    const float* h0 = (const float*)d_in[1];
    const float* c0 = (const float*)d_in[2];
    const float* emb = (const float*)d_in[3];
    const float* W_ih0 = (const float*)d_in[4];
    const float* W_hh0 = (const float*)d_in[5];
    const float* b_ih0 = (const float*)d_in[6];
    const float* b_hh0 = (const float*)d_in[7];
    const float* W_ih1 = (const float*)d_in[8];
    const float* W_hh1 = (const float*)d_in[9];
    const float* b_ih1 = (const float*)d_in[10];
    const float* b_hh1 = (const float*)d_in[11];
    const float* fc_W = (const float*)d_in[12];
    const float* fc_b = (const float*)d_in[13];
    float* out = (float*)d_out;
    float* ws = (float*)d_ws;

    // workspace layout (float offsets)
    const size_t OFF_G = 0;                                   // G0; later fc_W bf16
    const size_t OFF_X0H = OFF_G + (size_t)MROWS * GATES;     // u16 [4096][512]
    const size_t OFF_X0L = OFF_X0H + (size_t)MROWS * EMBED / 2;
    const size_t OFF_SEQ0 = OFF_X0L + (size_t)MROWS * EMBED / 2;
    const size_t SEQ_FLOATS = (size_t)2 * NSLOT * SEQ_SLOTU16 / 2;
    const size_t OFF_SEQ1 = OFF_SEQ0 + SEQ_FLOATS;
    const size_t OFF_WIHH = OFF_SEQ1 + SEQ_FLOATS;            // wih1 frag-order hi
    const size_t OFF_WIHL = OFF_WIHH + (size_t)GATES * HIDDEN / 2;
    const size_t OFF_W0H = OFF_WIHL + (size_t)GATES * HIDDEN / 2;  // wih0 hi
    const size_t OFF_W0L = OFF_W0H + (size_t)GATES * EMBED / 2;
    const size_t OFF_HT = OFF_W0L + (size_t)GATES * EMBED / 2;
    const size_t OFF_CT = OFF_HT + 2 * BATCH * HIDDEN;
    const size_t OFF_AR = OFF_CT + 2 * BATCH * HIDDEN;

    u16* x0H = (u16*)(ws + OFF_X0H);
    u16* x0L = (u16*)(ws + OFF_X0L);
    u16* seq0 = (u16*)(ws + OFF_SEQ0);
    u16* seq1 = (u16*)(ws + OFF_SEQ1);
    u16* wihH = (u16*)(ws + OFF_WIHH);
    u16* wihL = (u16*)(ws + OFF_WIHL);
    u16* w0H = (u16*)(ws + OFF_W0H);
    u16* w0L = (u16*)(ws + OFF_W0L);
    u32* arrive = (u32*)(ws + OFF_AR);

    init_state<<<128, 256, 0, stream>>>(h0, seq0, seq1, arrive);
    embed_hl_kernel<<<MROWS, 128, 0, stream>>>(x, emb, x0H, x0L);
    wih_swizzle_kernel<<<256, 256, 0, stream>>>(W_ih1, wihH, wihL);
    f32_to_bf16hl_kernel<<<2048, 256, 0, stream>>>(W_ih0, w0H, w0L, GATES * EMBED / 4);

    // layer-0 input projection via split-precision MFMA (includes both L0 biases)
    xproj_mfma<<<dim3(GATES / 128, MROWS / 128), 256, 0, stream>>>(
        x0H, x0L, w0H, w0L, b_ih0, b_hh0, ws + OFF_G);

    // fused balanced pipelined recurrence (both layers) — R11-proven kernel
    {
        const float* Whh0p = W_hh0;
        const float* Whh1p = W_hh1;
        const float* Gp = ws + OFF_G;
        const u16* wh = wihH;
        const u16* wl = wihL;
        const float* bi = b_ih1;
        const float* bh = b_hh1;
        const float* ci = c0;
        float* ct = ws + OFF_CT;
        float* ht = ws + OFF_HT;
        u16* s0 = seq0;
        u16* s1 = seq1;
        u32* ar = arrive;
        void* args[] = {(void*)&Whh0p, (void*)&Whh1p, (void*)&Gp, (void*)&wh,
                        (void*)&wl, (void*)&bi, (void*)&bh, (void*)&ci,
                        (void*)&ct, (void*)&ht, (void*)&s0, (void*)&s1, (void*)&ar};
        hipLaunchCooperativeKernel((void*)lstm_fused, dim3(256), dim3(256), args, 0, stream);
    }

    // FC via bf16 MFMA: A = seq1 hi slots 1..256 directly; B = fc_W bf16 (G0 dead)
    f32_to_bf16_kernel<<<4096, 256, 0, stream>>>(fc_W, (u16*)(ws + OFF_G), VOCAB * HIDDEN / 8);
    fc_mfma<<<dim3(VOCAB / 128, MROWS / 128), 256, 0, stream>>>(
        seq1 + SEQ_SLOTU16, (const u16*)(ws + OFF_G), fc_b, out);

    write_tails<<<128, 256, 0, stream>>>(ws + OFF_HT, ws + OFF_CT, out);
}